// Round 4
// baseline (706.512 us; speedup 1.0000x reference)
//
#include <hip/hip_runtime.h>
#include <cmath>

// Problem constants
#define D_MODEL 1024
#define KOSC    256
#define NSEQ    4096
#define BATCH   4
#define NROW    (BATCH * NSEQ)   // 16384 rows (b*n)
#define JTOT    1792             // 6K proj + K phase

typedef short      s16x8 __attribute__((ext_vector_type(8)));
typedef float      f32x4 __attribute__((ext_vector_type(4)));

// async global->LDS, 16B per lane; LDS dest = wave-uniform base + lane*16
#define GL2LDS(gsrc, ldst)                                                      \
  __builtin_amdgcn_global_load_lds(                                             \
      (const __attribute__((address_space(1))) unsigned int*)(gsrc),            \
      (__attribute__((address_space(3))) unsigned int*)(ldst), 16, 0, 0)

#define MFMA16(a, b, c) __builtin_amdgcn_mfma_f32_16x16x32_bf16((a), (b), (c), 0, 0, 0)

__device__ __forceinline__ float sigm(float x) {
    return 1.0f / (1.0f + expf(-x));
}
__device__ __forceinline__ float softplusf_(float x) {
    return fmaxf(x, 0.0f) + log1pf(expf(-fabsf(x)));
}

// round-to-nearest-even bf16 split: f = hi + lo, residual ~2^-18 * |f|
__device__ __forceinline__ void bf16_split(float f, unsigned short& hi,
                                           unsigned short& lo) {
    unsigned u = __float_as_uint(f);
    unsigned r = u + 0x7FFFu + ((u >> 16) & 1u);
    hi = (unsigned short)(r >> 16);
    float fh = __uint_as_float((unsigned)hi << 16);
    float fl = f - fh;
    unsigned ul = __float_as_uint(fl);
    unsigned rl = ul + 0x7FFFu + ((ul >> 16) & 1u);
    lo = (unsigned short)(rl >> 16);
}

// ---------------------------------------------------------------------------
// split_x: x fp32 (16384x1024) -> XH, XL bf16 (in d_out scratch)
// ---------------------------------------------------------------------------
__global__ __launch_bounds__(256) void split_x_kernel(
    const float* __restrict__ x, unsigned short* __restrict__ XH,
    unsigned short* __restrict__ XL)
{
    int i = blockIdx.x * 256 + threadIdx.x;    // x4 floats
    float4 v = ((const float4*)x)[i];
    ushort4 h, l;
    bf16_split(v.x, h.x, l.x);
    bf16_split(v.y, h.y, l.y);
    bf16_split(v.z, h.z, l.z);
    bf16_split(v.w, h.w, l.w);
    ((ushort4*)XH)[i] = h;
    ((ushort4*)XL)[i] = l;
}

// ---------------------------------------------------------------------------
// split_w: [Wproj;Wphase] fp32 (1792x1024) -> WH, WL bf16
// ---------------------------------------------------------------------------
__global__ __launch_bounds__(256) void split_w_kernel(
    const float* __restrict__ Wproj, const float* __restrict__ Wphase,
    unsigned short* __restrict__ WH, unsigned short* __restrict__ WL)
{
    int i = blockIdx.x * 256 + threadIdx.x;    // x4 floats
    int elem = i << 2;
    int row = elem >> 10;
    int col = elem & 1023;
    const float* src = (row < 1536) ? (Wproj + (size_t)row * 1024 + col)
                                    : (Wphase + (size_t)(row - 1536) * 1024 + col);
    float4 v = *(const float4*)src;
    ushort4 h, l;
    bf16_split(v.x, h.x, l.x);
    bf16_split(v.y, h.y, l.y);
    bf16_split(v.z, h.z, l.z);
    bf16_split(v.w, h.w, l.w);
    ((ushort4*)WH)[i] = h;
    ((ushort4*)WL)[i] = l;
}

// ---------------------------------------------------------------------------
// pack_wres: W_res fp32 (1024 x 1022) -> WPH bf16 (1024 x 1024), padded 0
// ---------------------------------------------------------------------------
__global__ __launch_bounds__(256) void pack_wres_kernel(
    const float* __restrict__ Wres, unsigned short* __restrict__ WPH)
{
    int idx = blockIdx.x * 256 + threadIdx.x;   // 0 .. 1024*1024-1
    int d = idx >> 10;
    int j = idx & 1023;
    float v = (j < 1022) ? Wres[(size_t)d * 1022 + j] : 0.0f;
    unsigned u = __float_as_uint(v);
    unsigned r = u + 0x7FFFu + ((u >> 16) & 1u);
    WPH[idx] = (unsigned short)(r >> 16);
}

// ===========================================================================
// 256-class GEMM cores: triple-buffered LDS, counted vmcnt (never 0 in-loop),
// one raw s_barrier per K-tile.
//
// Invariants (race-freedom):
//  * Each wave: s_waitcnt vmcnt(L) [L = loads/tile of tile t+1 still allowed
//    in flight] ensures its OWN tile-t loads landed; the following s_barrier
//    makes that collective (every wave stages a disjoint slice).
//  * stage(t+2) targets the buffer last READ at tile t-1; all those ds_reads
//    completed before each wave's tile-t barrier (MFMAs consumed them).
//  * In-loop waits never drain to 0: tile t+1's loads stay in flight across
//    the barrier (T3+T4). Final tile peeled with vmcnt(0).
//
// LDS layout per array: ksub-major granules [gq][row][8] — matches the
// linear gload_lds dest (wave-uniform base + lane*16) and gives 0-conflict
// ds_read_b128 (measured 0 in all rounds).
// ===========================================================================

// ---------------------------------------------------------------------------
// GEMM1-full (3-term split-bf16): PT rows 256..767 (omega, phi).
// BM=256 (W rows), BN=128 (x rows). 8 waves 4Mx2N, wave tile 64x64.
// Arrays: AH, AL (256rows=16KB), BH, BL (128rows=8KB): 48KB/tile x3 = 144KB.
// 6 gload_lds per thread per tile -> vmcnt(6). Grid (128, 2) = 256 blocks.
// ---------------------------------------------------------------------------
__global__ __launch_bounds__(512, 2) void gemm1_full_kernel(
    const unsigned short* __restrict__ WH, const unsigned short* __restrict__ WL,
    const unsigned short* __restrict__ XH, const unsigned short* __restrict__ XL,
    const float* __restrict__ bproj, float* __restrict__ PT)
{
    // per buf (shorts): AH [0,8192) AL [8192,16384) BH [16384,20480) BL [20480,24576)
    __shared__ __attribute__((aligned(16))) unsigned short smem[3 * 24576]; // 144 KB

    const int tid  = threadIdx.x;
    const int lane = tid & 63;
    const int w    = tid >> 6;          // 0..7
    const int wm   = w >> 1;            // 0..3
    const int wn   = w & 1;             // 0..1
    const int m0   = (blockIdx.y + 1) * 256;   // rows 256..767
    const int n0   = blockIdx.x * 128;
    const int fr   = lane & 15;
    const int fq   = lane >> 4;

    f32x4 acc[4][4];
    #pragma unroll
    for (int i = 0; i < 4; i++)
        #pragma unroll
        for (int j = 0; j < 4; j++) acc[i][j] = (f32x4){0.f, 0.f, 0.f, 0.f};

    auto STAGE = [&](int b, int t) {
        const int kb = t * 32;
        const int base = b * 24576;
        #pragma unroll
        for (int it = 0; it < 2; it++) {            // A: 1024 granules
            int G   = it * 512 + tid;
            int row = G & 255;
            int gq  = G >> 8;
            size_t offA = (size_t)(m0 + row) * 1024 + kb + gq * 8;
            int gb = (it * 512 + w * 64) * 8;       // wave-uniform
            GL2LDS(WH + offA, &smem[base + gb]);
            GL2LDS(WL + offA, &smem[base + 8192 + gb]);
        }
        {                                           // B: 512 granules
            int G   = tid;
            int row = G & 127;
            int gq  = G >> 7;
            size_t offB = (size_t)(n0 + row) * 1024 + kb + gq * 8;
            int gb = (w * 64) * 8;
            GL2LDS(XH + offB, &smem[base + 16384 + gb]);
            GL2LDS(XL + offB, &smem[base + 20480 + gb]);
        }
    };

    auto TILE = [&](int b) {
        const int base = b * 24576;
        s16x8 ah[4], al[4], bh[4], bl[4];
        #pragma unroll
        for (int i = 0; i < 4; i++) {
            int g = (fq * 256 + wm * 64 + i * 16 + fr) * 8;
            ah[i] = *(const s16x8*)&smem[base + g];
            al[i] = *(const s16x8*)&smem[base + 8192 + g];
        }
        #pragma unroll
        for (int j = 0; j < 4; j++) {
            int g = (fq * 128 + wn * 64 + j * 16 + fr) * 8;
            bh[j] = *(const s16x8*)&smem[base + 16384 + g];
            bl[j] = *(const s16x8*)&smem[base + 20480 + g];
        }
        __builtin_amdgcn_s_setprio(1);
        #pragma unroll
        for (int i = 0; i < 4; i++)
            #pragma unroll
            for (int j = 0; j < 4; j++) {
                acc[i][j] = MFMA16(ah[i], bh[j], acc[i][j]);
                acc[i][j] = MFMA16(ah[i], bl[j], acc[i][j]);
                acc[i][j] = MFMA16(al[i], bh[j], acc[i][j]);
            }
        __builtin_amdgcn_s_setprio(0);
    };

    STAGE(0, 0);
    STAGE(1, 1);
    int bc = 0, bs = 2;
    for (int t = 0; t < 31; t++) {
        asm volatile("s_waitcnt vmcnt(6)" ::: "memory");
        __builtin_amdgcn_s_barrier();
        if (t < 30) STAGE(bs, t + 2);
        TILE(bc);
        bc = (bc == 2) ? 0 : bc + 1;
        bs = (bs == 2) ? 0 : bs + 1;
    }
    asm volatile("s_waitcnt vmcnt(0)" ::: "memory");
    __builtin_amdgcn_s_barrier();
    TILE(bc);

    #pragma unroll
    for (int i = 0; i < 4; i++) {
        int mbase = m0 + wm * 64 + i * 16 + fq * 4;
        #pragma unroll
        for (int j = 0; j < 4; j++) {
            int n = n0 + wn * 64 + j * 16 + fr;
            #pragma unroll
            for (int rg = 0; rg < 4; rg++) {
                int m = mbase + rg;
                PT[(size_t)m * NROW + n] = acc[i][j][rg] + bproj[m];
            }
        }
    }
}

// ---------------------------------------------------------------------------
// GEMM1-lite (single bf16): PT rows 0..255, 768..1791.
// BM=BN=256, 8 waves 2Mx4N, wave tile 128x64. Arrays AH, BH (16KB each):
// 32KB/tile x3 = 96KB. 4 loads/thread/tile -> vmcnt(4). Grid (64, 5).
// ---------------------------------------------------------------------------
__global__ __launch_bounds__(512, 2) void gemm1_lite_kernel(
    const unsigned short* __restrict__ WH, const unsigned short* __restrict__ XH,
    const float* __restrict__ bproj, const float* __restrict__ bphase,
    float* __restrict__ PT)
{
    // per buf (shorts): AH [0,8192) BH [8192,16384)
    __shared__ __attribute__((aligned(16))) unsigned short smem[3 * 16384]; // 96 KB

    const int tid  = threadIdx.x;
    const int lane = tid & 63;
    const int w    = tid >> 6;
    const int wm   = w >> 2;            // 0..1
    const int wn   = w & 3;             // 0..3
    const int yt   = blockIdx.y;        // 0..4
    const int m0   = (yt == 0) ? 0 : (512 + yt * 256);  // 0,768,1024,1280,1536
    const int n0   = blockIdx.x * 256;
    const int fr   = lane & 15;
    const int fq   = lane >> 4;

    f32x4 acc[8][4];
    #pragma unroll
    for (int i = 0; i < 8; i++)
        #pragma unroll
        for (int j = 0; j < 4; j++) acc[i][j] = (f32x4){0.f, 0.f, 0.f, 0.f};

    auto STAGE = [&](int b, int t) {
        const int kb = t * 32;
        const int base = b * 16384;
        #pragma unroll
        for (int it = 0; it < 2; it++) {
            int G   = it * 512 + tid;
            int row = G & 255;
            int gq  = G >> 8;
            size_t offA = (size_t)(m0 + row) * 1024 + kb + gq * 8;
            size_t offB = (size_t)(n0 + row) * 1024 + kb + gq * 8;
            int gb = (it * 512 + w * 64) * 8;
            GL2LDS(WH + offA, &smem[base + gb]);
            GL2LDS(XH + offB, &smem[base + 8192 + gb]);
        }
    };

    auto TILE = [&](int b) {
        const int base = b * 16384;
        s16x8 ah[8], bh[4];
        #pragma unroll
        for (int i = 0; i < 8; i++)
            ah[i] = *(const s16x8*)&smem[base + (fq * 256 + wm * 128 + i * 16 + fr) * 8];
        #pragma unroll
        for (int j = 0; j < 4; j++)
            bh[j] = *(const s16x8*)&smem[base + 8192 + (fq * 256 + wn * 64 + j * 16 + fr) * 8];
        __builtin_amdgcn_s_setprio(1);
        #pragma unroll
        for (int i = 0; i < 8; i++)
            #pragma unroll
            for (int j = 0; j < 4; j++)
                acc[i][j] = MFMA16(ah[i], bh[j], acc[i][j]);
        __builtin_amdgcn_s_setprio(0);
    };

    STAGE(0, 0);
    STAGE(1, 1);
    int bc = 0, bs = 2;
    for (int t = 0; t < 31; t++) {
        asm volatile("s_waitcnt vmcnt(4)" ::: "memory");
        __builtin_amdgcn_s_barrier();
        if (t < 30) STAGE(bs, t + 2);
        TILE(bc);
        bc = (bc == 2) ? 0 : bc + 1;
        bs = (bs == 2) ? 0 : bs + 1;
    }
    asm volatile("s_waitcnt vmcnt(0)" ::: "memory");
    __builtin_amdgcn_s_barrier();
    TILE(bc);

    #pragma unroll
    for (int i = 0; i < 8; i++) {
        int mbase = m0 + wm * 128 + i * 16 + fq * 4;
        #pragma unroll
        for (int j = 0; j < 4; j++) {
            int n = n0 + wn * 64 + j * 16 + fr;
            #pragma unroll
            for (int rg = 0; rg < 4; rg++) {
                int m = mbase + rg;
                float bias = (m < 1536) ? bproj[m] : bphase[m - 1536];
                PT[(size_t)m * NROW + n] = acc[i][j][rg] + bias;
            }
        }
    }
}

// ---------------------------------------------------------------------------
// Scan kernel: one block per (b, k) channel. cs/sn carried in registers
// between pass 1 and pass 3.
// ---------------------------------------------------------------------------
__global__ __launch_bounds__(256) void scan_kernel(float* PT,
                                                   const float* lambda_ptr)
{
    const int bx = blockIdx.x;         // 0..1023
    const int k = bx & 255;
    const int b = bx >> 8;
    const int t = threadIdx.x;         // 0..255
    const size_t colb = (size_t)b * NSEQ;
    const size_t R = NROW;

    float* rowA  = PT + (size_t)(k)        * R + colb;  // a_raw -> rho_re
    float* rowW  = PT + (size_t)(256 + k)  * R + colb;  // w_raw -> rho_im
    float* rowP  = PT + (size_t)(512 + k)  * R + colb;  // p_raw -> g
    float* rowAl = PT + (size_t)(768 + k)  * R + colb;  // al_raw
    float* rowG  = PT + (size_t)(1024 + k) * R + colb;  // g_raw
    float* rowBe = PT + (size_t)(1280 + k) * R + colb;  // be_raw
    float* rowPq = PT + (size_t)(1536 + k) * R + colb;  // phase query

    __shared__ float s_al[NSEQ + 256];
    __shared__ float s_rr[NSEQ + 256];
    __shared__ float s_ri[NSEQ + 256];
    __shared__ float s_sa[256], s_sbr[256], s_sbi[256];

    const float lam = *lambda_ptr;

    float cs_r[16], sn_r[16];          // fully unrolled -> stays in VGPRs

    #pragma unroll
    for (int i = 0; i < 16; i++) {
        int n = i * 256 + t;
        float araw = rowA[n];
        float wraw = rowW[n];
        float praw = rowP[n];
        float alraw = rowAl[n];
        float A     = 3.0f * sigm(araw);
        float alpha = sigm(alraw);
        float omega = softplusf_(wraw);
        float ang   = fmaf(omega, log1pf((float)n), praw);
        float sn, cs;
        sincosf(ang, &sn, &cs);
        cs_r[i] = cs;
        sn_r[i] = sn;
        float amp = (1.0f - alpha) * A;
        int pidx = n + (n >> 4);
        s_al[pidx] = alpha;
        s_rr[pidx] = amp * cs;
        s_ri[pidx] = amp * sn;
    }
    __syncthreads();

    {
        float ap = 1.0f, br = 0.0f, bi = 0.0f;
        int base = t * 17;
        #pragma unroll
        for (int i = 0; i < 16; i++) {
            float a = s_al[base + i];
            br = fmaf(a, br, s_rr[base + i]);
            bi = fmaf(a, bi, s_ri[base + i]);
            ap *= a;
        }
        s_sa[t] = ap; s_sbr[t] = br; s_sbi[t] = bi;
    }
    __syncthreads();

    for (int off = 1; off < 256; off <<= 1) {
        float a2 = s_sa[t], b2r = s_sbr[t], b2i = s_sbi[t];
        float a1 = 1.0f, b1r = 0.0f, b1i = 0.0f;
        if (t >= off) { a1 = s_sa[t - off]; b1r = s_sbr[t - off]; b1i = s_sbi[t - off]; }
        __syncthreads();
        s_sa[t]  = a1 * a2;
        s_sbr[t] = fmaf(a2, b1r, b2r);
        s_sbi[t] = fmaf(a2, b1i, b2i);
        __syncthreads();
    }

    {
        float cr = 0.0f, ci = 0.0f;
        if (t > 0) { cr = s_sbr[t - 1]; ci = s_sbi[t - 1]; }
        int base = t * 17;
        #pragma unroll
        for (int i = 0; i < 16; i++) {
            float a = s_al[base + i];
            cr = fmaf(a, cr, s_rr[base + i]);
            ci = fmaf(a, ci, s_ri[base + i]);
            s_rr[base + i] = cr;
            s_ri[base + i] = ci;
        }
    }
    __syncthreads();

    #pragma unroll
    for (int i = 0; i < 16; i++) {
        int n = i * 256 + t;
        float beraw = rowBe[n];
        float graw = rowG[n];
        float pq = rowPq[n];

        float cs = cs_r[i];
        float sn = sn_r[i];

        int pidx = n + (n >> 4);
        float rr = s_rr[pidx], ri = s_ri[pidx];
        float beta = sigm(beraw);
        float g = sigm(graw);

        float readout = rr * cs + ri * sn;
        rr -= beta * readout * cs;
        ri -= beta * readout * sn;

        float modulus = sqrtf(rr * rr + ri * ri + 1e-8f);
        float scale = fmaxf(modulus, 1.0f);
        rr /= scale; ri /= scale;

        float rho_re = rr * cs + ri * sn;
        float rho_im = -rr * sn + ri * cs;

        float rho_norm = sqrtf(rho_re * rho_re + rho_im * rho_im + 1e-8f);
        float sq, cq;
        sincosf(pq, &sq, &cq);
        float pa = (rho_re * cq + rho_im * sq) / rho_norm;
        float gate = sigm(lam * pa);
        rho_re *= gate;
        rho_im *= gate;

        rowA[n] = rho_re;
        rowW[n] = rho_im;
        rowP[n] = g;
    }
}

// ---------------------------------------------------------------------------
// pack_rho: fused cross-products + transpose + bf16 split.
// ---------------------------------------------------------------------------
__global__ __launch_bounds__(256) void pack_rho_kernel(
    const float* __restrict__ PT, unsigned short* __restrict__ RTH,
    unsigned short* __restrict__ RTL)
{
    __shared__ float s_re[256 * 33];
    __shared__ float s_im[256 * 33];
    __shared__ float s_g [256 * 33];

    const int tid = threadIdx.x;
    const int r0 = blockIdx.x * 32;

    {
        int lr = tid & 31;
        int k0 = tid >> 5;       // 0..7
        for (int it = 0; it < 32; it++) {
            int k = it * 8 + k0;
            size_t go = (size_t)k * NROW + r0 + lr;
            s_re[k * 33 + lr] = PT[go];
            s_im[k * 33 + lr] = PT[(size_t)256 * NROW + go];
            s_g [k * 33 + lr] = PT[(size_t)512 * NROW + go];
        }
    }
    __syncthreads();

    const int r = tid >> 3;      // 0..31
    const int c = tid & 7;       // 0..7
    for (int i = 0; i < 16; i++) {
        int jb = (c + 8 * i) * 8;       // 0..1016, step 8
        unsigned short h[8], l[8];
        #pragma unroll
        for (int e = 0; e < 8; e++) {
            int j = jb + e;
            float v;
            if (j < 256) {
                v = s_g[j * 33 + r] * s_re[j * 33 + r];
            } else if (j < 512) {
                int k = j - 256;
                v = s_g[k * 33 + r] * s_im[k * 33 + r];
            } else if (j < 767) {
                int k = j - 512;
                float gc = 0.5f * (s_g[k * 33 + r] + s_g[(k + 1) * 33 + r]);
                v = gc * (s_re[k * 33 + r] * s_re[(k + 1) * 33 + r]
                        - s_im[k * 33 + r] * s_im[(k + 1) * 33 + r]);
            } else if (j < 1022) {
                int k = j - 767;
                float gc = 0.5f * (s_g[k * 33 + r] + s_g[(k + 1) * 33 + r]);
                v = gc * (s_re[k * 33 + r] * s_im[(k + 1) * 33 + r]
                        + s_im[k * 33 + r] * s_re[(k + 1) * 33 + r]);
            } else {
                v = 0.0f;
            }
            bf16_split(v, h[e], l[e]);
        }
        size_t off = (size_t)(r0 + r) * 1024 + jb;
        s16x8 hv, lv;
        #pragma unroll
        for (int e = 0; e < 8; e++) { hv[e] = (short)h[e]; lv[e] = (short)l[e]; }
        *(s16x8*)&RTH[off] = hv;
        *(s16x8*)&RTL[off] = lv;
    }
}

// ---------------------------------------------------------------------------
// GEMM2 (2-term: W_res bf16, rho hi+lo): out[r,d] = rs * sum_j RT[r,j]*WP[d,j]
// BM=BN=256, 8 waves 2Mx4N, wave tile 128x64. Arrays AH, BH, BL (16KB each):
// 48KB/tile x3 = 144KB. 6 loads/thread/tile -> vmcnt(6).
// Grid (64, 4) = 256 blocks = exactly 1/CU.
// ---------------------------------------------------------------------------
__global__ __launch_bounds__(512, 2) void gemm2_kernel(
    const unsigned short* __restrict__ WPH,
    const unsigned short* __restrict__ RTH, const unsigned short* __restrict__ RTL,
    const float* __restrict__ rs_ptr, float* __restrict__ out)
{
    // per buf (shorts): AH [0,8192) BH [8192,16384) BL [16384,24576)
    __shared__ __attribute__((aligned(16))) unsigned short smem[3 * 24576]; // 144 KB

    const int tid  = threadIdx.x;
    const int lane = tid & 63;
    const int w    = tid >> 6;
    const int wm   = w >> 2;            // 0..1
    const int wn   = w & 3;             // 0..3
    const int m0   = blockIdx.y * 256;  // d tile
    const int n0   = blockIdx.x * 256;  // r tile
    const int fr   = lane & 15;
    const int fq   = lane >> 4;
    const float rs = *rs_ptr;

    f32x4 acc[8][4];
    #pragma unroll
    for (int i = 0; i < 8; i++)
        #pragma unroll
        for (int j = 0; j < 4; j++) acc[i][j] = (f32x4){0.f, 0.f, 0.f, 0.f};

    auto STAGE = [&](int b, int t) {
        const int kb = t * 32;
        const int base = b * 24576;
        #pragma unroll
        for (int it = 0; it < 2; it++) {
            int G   = it * 512 + tid;
            int row = G & 255;
            int gq  = G >> 8;
            size_t offA = (size_t)(m0 + row) * 1024 + kb + gq * 8;
            size_t offB = (size_t)(n0 + row) * 1024 + kb + gq * 8;
            int gb = (it * 512 + w * 64) * 8;
            GL2LDS(WPH + offA, &smem[base + gb]);
            GL2LDS(RTH + offB, &smem[base + 8192 + gb]);
            GL2LDS(RTL + offB, &smem[base + 16384 + gb]);
        }
    };

    auto TILE = [&](int b) {
        const int base = b * 24576;
        s16x8 ah[8], bh[4], bl[4];
        #pragma unroll
        for (int i = 0; i < 8; i++)
            ah[i] = *(const s16x8*)&smem[base + (fq * 256 + wm * 128 + i * 16 + fr) * 8];
        #pragma unroll
        for (int j = 0; j < 4; j++) {
            int g = (fq * 256 + wn * 64 + j * 16 + fr) * 8;
            bh[j] = *(const s16x8*)&smem[base + 8192 + g];
            bl[j] = *(const s16x8*)&smem[base + 16384 + g];
        }
        __builtin_amdgcn_s_setprio(1);
        #pragma unroll
        for (int i = 0; i < 8; i++)
            #pragma unroll
            for (int j = 0; j < 4; j++) {
                acc[i][j] = MFMA16(ah[i], bh[j], acc[i][j]);
                acc[i][j] = MFMA16(ah[i], bl[j], acc[i][j]);
            }
        __builtin_amdgcn_s_setprio(0);
    };

    STAGE(0, 0);
    STAGE(1, 1);
    int bc = 0, bs = 2;
    for (int t = 0; t < 31; t++) {
        asm volatile("s_waitcnt vmcnt(6)" ::: "memory");
        __builtin_amdgcn_s_barrier();
        if (t < 30) STAGE(bs, t + 2);
        TILE(bc);
        bc = (bc == 2) ? 0 : bc + 1;
        bs = (bs == 2) ? 0 : bs + 1;
    }
    asm volatile("s_waitcnt vmcnt(0)" ::: "memory");
    __builtin_amdgcn_s_barrier();
    TILE(bc);

    #pragma unroll
    for (int i = 0; i < 8; i++) {
        int d = m0 + wm * 128 + i * 16 + fq * 4;
        #pragma unroll
        for (int j = 0; j < 4; j++) {
            int n = n0 + wn * 64 + j * 16 + fr;
            float4 v = { rs * acc[i][j][0], rs * acc[i][j][1],
                         rs * acc[i][j][2], rs * acc[i][j][3] };
            *(float4*)&out[(size_t)n * 1024 + d] = v;
        }
    }
}

// ---------------------------------------------------------------------------
extern "C" void kernel_launch(void* const* d_in, const int* in_sizes, int n_in,
                              void* d_out, int out_size, void* d_ws, size_t ws_size,
                              hipStream_t stream)
{
    const float* x      = (const float*)d_in[0];
    const float* Wproj  = (const float*)d_in[1];
    const float* bproj  = (const float*)d_in[2];
    const float* Wres   = (const float*)d_in[3];
    const float* Wphase = (const float*)d_in[4];
    const float* bphase = (const float*)d_in[5];
    const float* lam    = (const float*)d_in[6];
    const float* rs     = (const float*)d_in[7];
    float* out = (float*)d_out;

    // workspace layout (~124.8 MB):
    //   PT fp32 [1792][16384]           (117.4 MB)
    //   WH, WL bf16 [1792][1024]        (7.3 MB, after PT)
    // aliased into dead PT rows:
    //   RTH bf16 [16384][1024] = PT rows  768..1279
    //   RTL bf16 [16384][1024] = PT rows 1280..1791
    //   WPH bf16 [1024][1024]  = PT rows 0..31 (after pack_rho)
    // d_out doubles as XH/XL bf16 scratch until gemm2 overwrites it.
    float* PT = (float*)d_ws;
    unsigned short* WH  = (unsigned short*)((char*)d_ws + (size_t)JTOT * NROW * 4);
    unsigned short* WL  = WH + (size_t)JTOT * 1024;
    unsigned short* RTH = (unsigned short*)(PT + (size_t)768 * NROW);
    unsigned short* RTL = RTH + (size_t)NROW * 1024;
    unsigned short* WPH = (unsigned short*)PT;
    unsigned short* XH  = (unsigned short*)d_out;
    unsigned short* XL  = XH + (size_t)NROW * 1024;

    hipLaunchKernelGGL(split_x_kernel, dim3(NROW * D_MODEL / 1024), dim3(256), 0, stream,
                       x, XH, XL);
    hipLaunchKernelGGL(split_w_kernel, dim3(JTOT * D_MODEL / 1024), dim3(256), 0, stream,
                       Wproj, Wphase, WH, WL);
    hipLaunchKernelGGL(gemm1_full_kernel, dim3(NROW / 128, 2), dim3(512), 0, stream,
                       WH, WL, XH, XL, bproj, PT);
    hipLaunchKernelGGL(gemm1_lite_kernel, dim3(NROW / 256, 5), dim3(512), 0, stream,
                       WH, XH, bproj, bphase, PT);
    hipLaunchKernelGGL(scan_kernel, dim3(BATCH * KOSC), dim3(256), 0, stream,
                       PT, lam);
    hipLaunchKernelGGL(pack_rho_kernel, dim3(NROW / 32), dim3(256), 0, stream,
                       PT, RTH, RTL);
    hipLaunchKernelGGL(pack_wres_kernel, dim3(1024 * 1024 / 256), dim3(256), 0, stream,
                       Wres, WPH);
    hipLaunchKernelGGL(gemm2_kernel, dim3(NROW / 256, 1024 / 256), dim3(512), 0, stream,
                       WPH, RTH, RTL, rs, out);
}

// Round 5
// 560.068 us; speedup vs baseline: 1.2615x; 1.2615x over previous
//
#include <hip/hip_runtime.h>
#include <cmath>

// Problem constants
#define D_MODEL 1024
#define KOSC    256
#define NSEQ    4096
#define BATCH   4
#define NROW    (BATCH * NSEQ)   // 16384 rows (b*n)
#define JTOT    1792             // 6K proj + K phase

typedef short      s16x8 __attribute__((ext_vector_type(8)));
typedef float      f32x4 __attribute__((ext_vector_type(4)));

// async global->LDS, 16B per lane; LDS dest = wave-uniform base + lane*16
#define GL2LDS(gsrc, ldst)                                                      \
  __builtin_amdgcn_global_load_lds(                                             \
      (const __attribute__((address_space(1))) unsigned int*)(gsrc),            \
      (__attribute__((address_space(3))) unsigned int*)(ldst), 16, 0, 0)

__device__ __forceinline__ float sigm(float x) {
    return 1.0f / (1.0f + expf(-x));
}
__device__ __forceinline__ float softplusf_(float x) {
    return fmaxf(x, 0.0f) + log1pf(expf(-fabsf(x)));
}

// round-to-nearest-even bf16 split: f = hi + lo, residual ~2^-18 * |f|
__device__ __forceinline__ void bf16_split(float f, unsigned short& hi,
                                           unsigned short& lo) {
    unsigned u = __float_as_uint(f);
    unsigned r = u + 0x7FFFu + ((u >> 16) & 1u);
    hi = (unsigned short)(r >> 16);
    float fh = __uint_as_float((unsigned)hi << 16);
    float fl = f - fh;
    unsigned ul = __float_as_uint(fl);
    unsigned rl = ul + 0x7FFFu + ((ul >> 16) & 1u);
    lo = (unsigned short)(rl >> 16);
}

// ---------------------------------------------------------------------------
// split_x: x fp32 (16384x1024) -> XH, XL bf16 (in d_out scratch)
// ---------------------------------------------------------------------------
__global__ __launch_bounds__(256) void split_x_kernel(
    const float* __restrict__ x, unsigned short* __restrict__ XH,
    unsigned short* __restrict__ XL)
{
    int i = blockIdx.x * 256 + threadIdx.x;    // x4 floats
    float4 v = ((const float4*)x)[i];
    ushort4 h, l;
    bf16_split(v.x, h.x, l.x);
    bf16_split(v.y, h.y, l.y);
    bf16_split(v.z, h.z, l.z);
    bf16_split(v.w, h.w, l.w);
    ((ushort4*)XH)[i] = h;
    ((ushort4*)XL)[i] = l;
}

// ---------------------------------------------------------------------------
// split_w: [Wproj;Wphase] fp32 (1792x1024) -> WH, WL bf16
// ---------------------------------------------------------------------------
__global__ __launch_bounds__(256) void split_w_kernel(
    const float* __restrict__ Wproj, const float* __restrict__ Wphase,
    unsigned short* __restrict__ WH, unsigned short* __restrict__ WL)
{
    int i = blockIdx.x * 256 + threadIdx.x;    // x4 floats
    int elem = i << 2;
    int row = elem >> 10;
    int col = elem & 1023;
    const float* src = (row < 1536) ? (Wproj + (size_t)row * 1024 + col)
                                    : (Wphase + (size_t)(row - 1536) * 1024 + col);
    float4 v = *(const float4*)src;
    ushort4 h, l;
    bf16_split(v.x, h.x, l.x);
    bf16_split(v.y, h.y, l.y);
    bf16_split(v.z, h.z, l.z);
    bf16_split(v.w, h.w, l.w);
    ((ushort4*)WH)[i] = h;
    ((ushort4*)WL)[i] = l;
}

// ---------------------------------------------------------------------------
// pack_wres: W_res fp32 (1024 x 1022) -> WPH bf16 (1024 x 1024), padded 0
// ---------------------------------------------------------------------------
__global__ __launch_bounds__(256) void pack_wres_kernel(
    const float* __restrict__ Wres, unsigned short* __restrict__ WPH)
{
    int idx = blockIdx.x * 256 + threadIdx.x;   // 0 .. 1024*1024-1
    int d = idx >> 10;
    int j = idx & 1023;
    float v = (j < 1022) ? Wres[(size_t)d * 1022 + j] : 0.0f;
    unsigned u = __float_as_uint(v);
    unsigned r = u + 0x7FFFu + ((u >> 16) & 1u);
    WPH[idx] = (unsigned short)(r >> 16);
}

// ---------------------------------------------------------------------------
// GEMM1-full (3-term split-bf16): PT rows 256..767 (omega, phi) — these feed
// the oscillator angle (amplified by log-position <= 8.3) and need ~fp32.
//   jt = blockIdx.y + 2
// (round-2 proven structure; schedule restructures were neutral/regressions)
// ---------------------------------------------------------------------------
__global__ __launch_bounds__(256, 3) void gemm1_full_kernel(
    const unsigned short* __restrict__ WH, const unsigned short* __restrict__ WL,
    const unsigned short* __restrict__ XH, const unsigned short* __restrict__ XL,
    const float* __restrict__ bproj, float* __restrict__ PT)
{
    __shared__ __attribute__((aligned(16))) unsigned short AH[4096];
    __shared__ __attribute__((aligned(16))) unsigned short AL[4096];
    __shared__ __attribute__((aligned(16))) unsigned short BH[4096];
    __shared__ __attribute__((aligned(16))) unsigned short BL[4096];

    const int tid  = threadIdx.x;
    const int lane = tid & 63;
    const int w    = tid >> 6;          // wave 0..3
    const int wm   = w >> 1, wn = w & 1;
    const int m0   = (blockIdx.y + 2) * 128;  // j tile (rows 256..767)
    const int n0   = blockIdx.x * 128;        // r tile
    const int fr   = lane & 15;
    const int fq   = lane >> 4;         // 0..3

    f32x4 acc[4][4];
    #pragma unroll
    for (int i = 0; i < 4; i++)
        #pragma unroll
        for (int j = 0; j < 4; j++) acc[i][j] = (f32x4){0.f, 0.f, 0.f, 0.f};

    for (int kc = 0; kc < 32; kc++) {
        const int kbase = kc * 32;
        __syncthreads();
        #pragma unroll
        for (int t = 0; t < 2; t++) {
            int G  = w * 128 + t * 64 + lane;       // granule index 0..511
            int gm = G & 127;
            int gq = G >> 7;
            size_t offA = (size_t)(m0 + gm) * 1024 + kbase + gq * 8;
            size_t offB = (size_t)(n0 + gm) * 1024 + kbase + gq * 8;
            int ldsg = (w * 128 + t * 64) * 8;      // wave-uniform base (shorts)
            GL2LDS(WH + offA, &AH[ldsg]);
            GL2LDS(WL + offA, &AL[ldsg]);
            GL2LDS(XH + offB, &BH[ldsg]);
            GL2LDS(XL + offB, &BL[ldsg]);
        }
        __syncthreads();

        s16x8 ah[4], al[4], bh[4], bl[4];
        #pragma unroll
        for (int f = 0; f < 4; f++) {
            int aoff = (fq * 128 + wm * 64 + f * 16 + fr) * 8;
            int boff = (fq * 128 + wn * 64 + f * 16 + fr) * 8;
            ah[f] = *(const s16x8*)&AH[aoff];
            al[f] = *(const s16x8*)&AL[aoff];
            bh[f] = *(const s16x8*)&BH[boff];
            bl[f] = *(const s16x8*)&BL[boff];
        }
        #pragma unroll
        for (int i = 0; i < 4; i++)
            #pragma unroll
            for (int j = 0; j < 4; j++) {
                acc[i][j] = __builtin_amdgcn_mfma_f32_16x16x32_bf16(ah[i], bh[j], acc[i][j], 0, 0, 0);
                acc[i][j] = __builtin_amdgcn_mfma_f32_16x16x32_bf16(ah[i], bl[j], acc[i][j], 0, 0, 0);
                acc[i][j] = __builtin_amdgcn_mfma_f32_16x16x32_bf16(al[i], bh[j], acc[i][j], 0, 0, 0);
            }
    }

    #pragma unroll
    for (int i = 0; i < 4; i++) {
        int mbase = m0 + wm * 64 + i * 16 + fq * 4;
        #pragma unroll
        for (int j = 0; j < 4; j++) {
            int n = n0 + wn * 64 + j * 16 + fr;
            #pragma unroll
            for (int rg = 0; rg < 4; rg++) {
                int m = mbase + rg;
                PT[(size_t)m * NROW + n] = acc[i][j][rg] + bproj[m];
            }
        }
    }
}

// ---------------------------------------------------------------------------
// GEMM1-lite (single bf16): PT rows 0..255, 768..1791. BK=64 (round-2 proven).
//   jt = (blockIdx.y < 2) ? blockIdx.y : blockIdx.y + 4
// ---------------------------------------------------------------------------
__global__ __launch_bounds__(256, 4) void gemm1_lite_kernel(
    const unsigned short* __restrict__ WH, const unsigned short* __restrict__ XH,
    const float* __restrict__ bproj, const float* __restrict__ bphase,
    float* __restrict__ PT)
{
    __shared__ __attribute__((aligned(16))) unsigned short AH[8192]; // 128x64
    __shared__ __attribute__((aligned(16))) unsigned short BH[8192];

    const int tid  = threadIdx.x;
    const int lane = tid & 63;
    const int w    = tid >> 6;
    const int wm   = w >> 1, wn = w & 1;
    const int yt   = blockIdx.y;
    const int jt   = (yt < 2) ? yt : yt + 4;
    const int m0   = jt * 128;
    const int n0   = blockIdx.x * 128;
    const int fr   = lane & 15;
    const int fq   = lane >> 4;

    f32x4 acc[4][4];
    #pragma unroll
    for (int i = 0; i < 4; i++)
        #pragma unroll
        for (int j = 0; j < 4; j++) acc[i][j] = (f32x4){0.f, 0.f, 0.f, 0.f};

    for (int kc = 0; kc < 16; kc++) {
        const int kbase = kc * 64;
        __syncthreads();
        #pragma unroll
        for (int t = 0; t < 4; t++) {
            int G  = t * 256 + tid;                 // granule index 0..1023
            int gm = G & 127;
            int gq = G >> 7;                        // ksub 0..7
            size_t offA = (size_t)(m0 + gm) * 1024 + kbase + gq * 8;
            size_t offB = (size_t)(n0 + gm) * 1024 + kbase + gq * 8;
            int ldsg = (t * 256 + w * 64) * 8;      // wave-uniform base (shorts)
            GL2LDS(WH + offA, &AH[ldsg]);
            GL2LDS(XH + offB, &BH[ldsg]);
        }
        __syncthreads();

        #pragma unroll
        for (int s = 0; s < 2; s++) {
            s16x8 ah[4], bh[4];
            #pragma unroll
            for (int f = 0; f < 4; f++) {
                int aoff = (((s * 4 + fq) * 128) + wm * 64 + f * 16 + fr) * 8;
                int boff = (((s * 4 + fq) * 128) + wn * 64 + f * 16 + fr) * 8;
                ah[f] = *(const s16x8*)&AH[aoff];
                bh[f] = *(const s16x8*)&BH[boff];
            }
            #pragma unroll
            for (int i = 0; i < 4; i++)
                #pragma unroll
                for (int j = 0; j < 4; j++)
                    acc[i][j] = __builtin_amdgcn_mfma_f32_16x16x32_bf16(ah[i], bh[j], acc[i][j], 0, 0, 0);
        }
    }

    #pragma unroll
    for (int i = 0; i < 4; i++) {
        int mbase = m0 + wm * 64 + i * 16 + fq * 4;
        #pragma unroll
        for (int j = 0; j < 4; j++) {
            int n = n0 + wn * 64 + j * 16 + fr;
            #pragma unroll
            for (int rg = 0; rg < 4; rg++) {
                int m = mbase + rg;
                float bias = (m < 1536) ? bproj[m] : bphase[m - 1536];
                PT[(size_t)m * NROW + n] = acc[i][j][rg] + bias;
            }
        }
    }
}

// ---------------------------------------------------------------------------
// Scan kernel v2: register-resident. One block per (b,k) channel; thread t
// owns the contiguous chunk n = t*16 .. t*16+15.
//  * loads/stores via 4x float4 per row (wave covers a contiguous 4KB region
//    in 4 instructions; L2 absorbs the intra-line split)
//  * alpha/drive/cos/sin live in VGPRs across the scan
//  * block scan = intra-wave Kogge-Stone via __shfl_up + 48B LDS wave
//    aggregate exchange -> ONE __syncthreads, ~0 bank conflicts
// ---------------------------------------------------------------------------
__global__ __launch_bounds__(256, 3) void scan_kernel(float* PT,
                                                      const float* lambda_ptr)
{
    const int bx = blockIdx.x;         // 0..1023
    const int k = bx & 255;
    const int b = bx >> 8;
    const int t = threadIdx.x;         // 0..255
    const int lane = t & 63;
    const int wv = t >> 6;             // 0..3
    const size_t colb = (size_t)b * NSEQ;
    const size_t R = NROW;
    const int n0 = t * 16;

    float* rowA  = PT + (size_t)(k)        * R + colb + n0;  // a_raw -> rho_re
    float* rowW  = PT + (size_t)(256 + k)  * R + colb + n0;  // w_raw -> rho_im
    float* rowP  = PT + (size_t)(512 + k)  * R + colb + n0;  // p_raw -> g
    float* rowAl = PT + (size_t)(768 + k)  * R + colb + n0;  // al_raw
    float* rowG  = PT + (size_t)(1024 + k) * R + colb + n0;  // g_raw
    float* rowBe = PT + (size_t)(1280 + k) * R + colb + n0;  // be_raw
    float* rowPq = PT + (size_t)(1536 + k) * R + colb + n0;  // phase query

    __shared__ float s_a[4], s_br[4], s_bi[4];

    const float lam = *lambda_ptr;

    float al_r[16], rr_r[16], ri_r[16], cs_r[16], sn_r[16];

    // ---- pass 1: load own chunk, compute alpha/drive/cos/sin + local serial
    float fa[16], fw[16], fp[16], fl[16];
    #pragma unroll
    for (int q = 0; q < 4; q++) {
        *(float4*)&fa[q * 4] = ((const float4*)rowA)[q];
        *(float4*)&fw[q * 4] = ((const float4*)rowW)[q];
        *(float4*)&fp[q * 4] = ((const float4*)rowP)[q];
        *(float4*)&fl[q * 4] = ((const float4*)rowAl)[q];
    }
    float ap = 1.0f, br = 0.0f, bi = 0.0f;
    #pragma unroll
    for (int i = 0; i < 16; i++) {
        float A     = 3.0f * sigm(fa[i]);
        float alpha = sigm(fl[i]);
        float omega = softplusf_(fw[i]);
        float ang   = fmaf(omega, log1pf((float)(n0 + i)), fp[i]);
        float sn, cs;
        sincosf(ang, &sn, &cs);
        float amp = (1.0f - alpha) * A;
        float dr = amp * cs, di = amp * sn;
        al_r[i] = alpha; cs_r[i] = cs; sn_r[i] = sn;
        rr_r[i] = dr;    ri_r[i] = di;
        br = fmaf(alpha, br, dr);
        bi = fmaf(alpha, bi, di);
        ap *= alpha;
    }

    // ---- intra-wave inclusive Kogge-Stone scan of (ap, br, bi)
    #pragma unroll
    for (int off = 1; off < 64; off <<= 1) {
        float pa  = __shfl_up(ap, off);
        float pbr = __shfl_up(br, off);
        float pbi = __shfl_up(bi, off);
        if (lane >= off) {
            br = fmaf(ap, pbr, br);     // B = A_self*B_prev + B_self
            bi = fmaf(ap, pbi, bi);
            ap *= pa;
        }
    }

    // ---- cross-wave composition via 4-entry LDS
    if (lane == 63) { s_a[wv] = ap; s_br[wv] = br; s_bi[wv] = bi; }
    __syncthreads();
    float cbr = 0.0f, cbi = 0.0f;       // fold waves 0..wv-1 (left to right)
    #pragma unroll
    for (int u = 0; u < 3; u++) {
        if (u < wv) {
            cbr = fmaf(s_a[u], cbr, s_br[u]);
            cbi = fmaf(s_a[u], cbi, s_bi[u]);
        }
    }
    // exclusive intra-wave prefix
    float ea  = __shfl_up(ap, 1);
    float ebr = __shfl_up(br, 1);
    float ebi = __shfl_up(bi, 1);
    if (lane == 0) { ea = 1.0f; ebr = 0.0f; ebi = 0.0f; }
    float cr = fmaf(ea, cbr, ebr);      // r_{n0-1}
    float ci = fmaf(ea, cbi, ebi);

    // ---- local prefix completion (in registers)
    #pragma unroll
    for (int i = 0; i < 16; i++) {
        cr = fmaf(al_r[i], cr, rr_r[i]);
        ci = fmaf(al_r[i], ci, ri_r[i]);
        rr_r[i] = cr;
        ri_r[i] = ci;
    }

    // ---- pass 3: erase, norm, demodulate, gate; write rho_re/rho_im/g
    float fbe[16], fg[16], fq_[16];
    #pragma unroll
    for (int q = 0; q < 4; q++) {
        *(float4*)&fbe[q * 4] = ((const float4*)rowBe)[q];
        *(float4*)&fg[q * 4]  = ((const float4*)rowG)[q];
        *(float4*)&fq_[q * 4] = ((const float4*)rowPq)[q];
    }
    float ore[16], oim[16], og[16];
    #pragma unroll
    for (int i = 0; i < 16; i++) {
        float cs = cs_r[i], sn = sn_r[i];
        float rr = rr_r[i], ri = ri_r[i];
        float beta = sigm(fbe[i]);
        float g = sigm(fg[i]);

        float readout = rr * cs + ri * sn;
        rr -= beta * readout * cs;
        ri -= beta * readout * sn;

        float modulus = sqrtf(rr * rr + ri * ri + 1e-8f);
        float scale = fmaxf(modulus, 1.0f);
        rr /= scale; ri /= scale;

        float rho_re = rr * cs + ri * sn;
        float rho_im = -rr * sn + ri * cs;

        float rho_norm = sqrtf(rho_re * rho_re + rho_im * rho_im + 1e-8f);
        float sq, cq;
        sincosf(fq_[i], &sq, &cq);
        float pa2 = (rho_re * cq + rho_im * sq) / rho_norm;
        float gate = sigm(lam * pa2);
        ore[i] = gate * rho_re;
        oim[i] = gate * rho_im;
        og[i]  = g;
    }
    #pragma unroll
    for (int q = 0; q < 4; q++) {
        ((float4*)rowA)[q] = *(const float4*)&ore[q * 4];
        ((float4*)rowW)[q] = *(const float4*)&oim[q * 4];
        ((float4*)rowP)[q] = *(const float4*)&og[q * 4];
    }
}

// ---------------------------------------------------------------------------
// pack_rho: fused cross-products + transpose + bf16 split.
// ---------------------------------------------------------------------------
__global__ __launch_bounds__(256) void pack_rho_kernel(
    const float* __restrict__ PT, unsigned short* __restrict__ RTH,
    unsigned short* __restrict__ RTL)
{
    __shared__ float s_re[256 * 33];
    __shared__ float s_im[256 * 33];
    __shared__ float s_g [256 * 33];

    const int tid = threadIdx.x;
    const int r0 = blockIdx.x * 32;

    {
        int lr = tid & 31;
        int k0 = tid >> 5;       // 0..7
        for (int it = 0; it < 32; it++) {
            int k = it * 8 + k0;
            size_t go = (size_t)k * NROW + r0 + lr;
            s_re[k * 33 + lr] = PT[go];
            s_im[k * 33 + lr] = PT[(size_t)256 * NROW + go];
            s_g [k * 33 + lr] = PT[(size_t)512 * NROW + go];
        }
    }
    __syncthreads();

    const int r = tid >> 3;      // 0..31
    const int c = tid & 7;       // 0..7
    for (int i = 0; i < 16; i++) {
        int jb = (c + 8 * i) * 8;       // 0..1016, step 8
        unsigned short h[8], l[8];
        #pragma unroll
        for (int e = 0; e < 8; e++) {
            int j = jb + e;
            float v;
            if (j < 256) {
                v = s_g[j * 33 + r] * s_re[j * 33 + r];
            } else if (j < 512) {
                int k = j - 256;
                v = s_g[k * 33 + r] * s_im[k * 33 + r];
            } else if (j < 767) {
                int k = j - 512;
                float gc = 0.5f * (s_g[k * 33 + r] + s_g[(k + 1) * 33 + r]);
                v = gc * (s_re[k * 33 + r] * s_re[(k + 1) * 33 + r]
                        - s_im[k * 33 + r] * s_im[(k + 1) * 33 + r]);
            } else if (j < 1022) {
                int k = j - 767;
                float gc = 0.5f * (s_g[k * 33 + r] + s_g[(k + 1) * 33 + r]);
                v = gc * (s_re[k * 33 + r] * s_im[(k + 1) * 33 + r]
                        + s_im[k * 33 + r] * s_re[(k + 1) * 33 + r]);
            } else {
                v = 0.0f;
            }
            bf16_split(v, h[e], l[e]);
        }
        size_t off = (size_t)(r0 + r) * 1024 + jb;
        s16x8 hv, lv;
        #pragma unroll
        for (int e = 0; e < 8; e++) { hv[e] = (short)h[e]; lv[e] = (short)l[e]; }
        *(s16x8*)&RTH[off] = hv;
        *(s16x8*)&RTL[off] = lv;
    }
}

// ---------------------------------------------------------------------------
// GEMM2 (2-term: W_res bf16, rho hi+lo): out[r,d] = rs * sum_j RT[r,j]*WP[d,j]
// (round-2 proven structure)
// ---------------------------------------------------------------------------
__global__ __launch_bounds__(256, 3) void gemm2_kernel(
    const unsigned short* __restrict__ WPH,
    const unsigned short* __restrict__ RTH, const unsigned short* __restrict__ RTL,
    const float* __restrict__ rs_ptr, float* __restrict__ out)
{
    __shared__ __attribute__((aligned(16))) unsigned short AH[4096];
    __shared__ __attribute__((aligned(16))) unsigned short BH[4096];
    __shared__ __attribute__((aligned(16))) unsigned short BL[4096];

    const int tid  = threadIdx.x;
    const int lane = tid & 63;
    const int w    = tid >> 6;
    const int wm   = w >> 1, wn = w & 1;
    const int m0   = blockIdx.y * 128;  // d tile
    const int n0   = blockIdx.x * 128;  // r tile
    const int fr   = lane & 15;
    const int fq   = lane >> 4;
    const float rs = *rs_ptr;

    f32x4 acc[4][4];
    #pragma unroll
    for (int i = 0; i < 4; i++)
        #pragma unroll
        for (int j = 0; j < 4; j++) acc[i][j] = (f32x4){0.f, 0.f, 0.f, 0.f};

    for (int kc = 0; kc < 32; kc++) {
        const int kbase = kc * 32;
        __syncthreads();
        #pragma unroll
        for (int t = 0; t < 2; t++) {
            int G  = w * 128 + t * 64 + lane;
            int gm = G & 127;
            int gq = G >> 7;
            size_t offA = (size_t)(m0 + gm) * 1024 + kbase + gq * 8;
            size_t offB = (size_t)(n0 + gm) * 1024 + kbase + gq * 8;
            int ldsg = (w * 128 + t * 64) * 8;
            GL2LDS(WPH + offA, &AH[ldsg]);
            GL2LDS(RTH + offB, &BH[ldsg]);
            GL2LDS(RTL + offB, &BL[ldsg]);
        }
        __syncthreads();

        s16x8 ah[4], bh[4], bl[4];
        #pragma unroll
        for (int f = 0; f < 4; f++) {
            int aoff = (fq * 128 + wm * 64 + f * 16 + fr) * 8;
            int boff = (fq * 128 + wn * 64 + f * 16 + fr) * 8;
            ah[f] = *(const s16x8*)&AH[aoff];
            bh[f] = *(const s16x8*)&BH[boff];
            bl[f] = *(const s16x8*)&BL[boff];
        }
        #pragma unroll
        for (int i = 0; i < 4; i++)
            #pragma unroll
            for (int j = 0; j < 4; j++) {
                acc[i][j] = __builtin_amdgcn_mfma_f32_16x16x32_bf16(ah[i], bh[j], acc[i][j], 0, 0, 0);
                acc[i][j] = __builtin_amdgcn_mfma_f32_16x16x32_bf16(ah[i], bl[j], acc[i][j], 0, 0, 0);
            }
    }

    #pragma unroll
    for (int i = 0; i < 4; i++) {
        int d = m0 + wm * 64 + i * 16 + fq * 4;
        #pragma unroll
        for (int j = 0; j < 4; j++) {
            int n = n0 + wn * 64 + j * 16 + fr;
            float4 v = { rs * acc[i][j][0], rs * acc[i][j][1],
                         rs * acc[i][j][2], rs * acc[i][j][3] };
            *(float4*)&out[(size_t)n * 1024 + d] = v;
        }
    }
}

// ---------------------------------------------------------------------------
extern "C" void kernel_launch(void* const* d_in, const int* in_sizes, int n_in,
                              void* d_out, int out_size, void* d_ws, size_t ws_size,
                              hipStream_t stream)
{
    const float* x      = (const float*)d_in[0];
    const float* Wproj  = (const float*)d_in[1];
    const float* bproj  = (const float*)d_in[2];
    const float* Wres   = (const float*)d_in[3];
    const float* Wphase = (const float*)d_in[4];
    const float* bphase = (const float*)d_in[5];
    const float* lam    = (const float*)d_in[6];
    const float* rs     = (const float*)d_in[7];
    float* out = (float*)d_out;

    // workspace layout (~124.8 MB):
    //   PT fp32 [1792][16384]           (117.4 MB)
    //   WH, WL bf16 [1792][1024]        (7.3 MB, after PT)
    // aliased into dead PT rows:
    //   RTH bf16 [16384][1024] = PT rows  768..1279
    //   RTL bf16 [16384][1024] = PT rows 1280..1791
    //   WPH bf16 [1024][1024]  = PT rows 0..31 (after pack_rho)
    // d_out doubles as XH/XL bf16 scratch until gemm2 overwrites it.
    float* PT = (float*)d_ws;
    unsigned short* WH  = (unsigned short*)((char*)d_ws + (size_t)JTOT * NROW * 4);
    unsigned short* WL  = WH + (size_t)JTOT * 1024;
    unsigned short* RTH = (unsigned short*)(PT + (size_t)768 * NROW);
    unsigned short* RTL = RTH + (size_t)NROW * 1024;
    unsigned short* WPH = (unsigned short*)PT;
    unsigned short* XH  = (unsigned short*)d_out;
    unsigned short* XL  = XH + (size_t)NROW * 1024;

    hipLaunchKernelGGL(split_x_kernel, dim3(NROW * D_MODEL / 1024), dim3(256), 0, stream,
                       x, XH, XL);
    hipLaunchKernelGGL(split_w_kernel, dim3(JTOT * D_MODEL / 1024), dim3(256), 0, stream,
                       Wproj, Wphase, WH, WL);
    hipLaunchKernelGGL(gemm1_full_kernel, dim3(NROW / 128, 4), dim3(256), 0, stream,
                       WH, WL, XH, XL, bproj, PT);
    hipLaunchKernelGGL(gemm1_lite_kernel, dim3(NROW / 128, 10), dim3(256), 0, stream,
                       WH, XH, bproj, bphase, PT);
    hipLaunchKernelGGL(scan_kernel, dim3(BATCH * KOSC), dim3(256), 0, stream,
                       PT, lam);
    hipLaunchKernelGGL(pack_rho_kernel, dim3(NROW / 32), dim3(256), 0, stream,
                       PT, RTH, RTL);
    hipLaunchKernelGGL(pack_wres_kernel, dim3(1024 * 1024 / 256), dim3(256), 0, stream,
                       Wres, WPH);
    hipLaunchKernelGGL(gemm2_kernel, dim3(NROW / 128, 1024 / 128), dim3(256), 0, stream,
                       WPH, RTH, RTL, rs, out);
}

// Round 6
// 539.340 us; speedup vs baseline: 1.3100x; 1.0384x over previous
//
#include <hip/hip_runtime.h>
#include <cmath>

// Problem constants
#define D_MODEL 1024
#define KOSC    256
#define NSEQ    4096
#define BATCH   4
#define NROW    (BATCH * NSEQ)   // 16384 rows (b*n)
#define JTOT    1792             // 6K proj + K phase

typedef short      s16x8 __attribute__((ext_vector_type(8)));
typedef float      f32x4 __attribute__((ext_vector_type(4)));

// async global->LDS, 16B per lane; LDS dest = wave-uniform base + lane*16
#define GL2LDS(gsrc, ldst)                                                      \
  __builtin_amdgcn_global_load_lds(                                             \
      (const __attribute__((address_space(1))) unsigned int*)(gsrc),            \
      (__attribute__((address_space(3))) unsigned int*)(ldst), 16, 0, 0)

__device__ __forceinline__ float sigm(float x) {
    return 1.0f / (1.0f + expf(-x));
}
__device__ __forceinline__ float softplusf_(float x) {
    return fmaxf(x, 0.0f) + log1pf(expf(-fabsf(x)));
}

// round-to-nearest-even bf16 split: f = hi + lo, residual ~2^-18 * |f|
__device__ __forceinline__ void bf16_split(float f, unsigned short& hi,
                                           unsigned short& lo) {
    unsigned u = __float_as_uint(f);
    unsigned r = u + 0x7FFFu + ((u >> 16) & 1u);
    hi = (unsigned short)(r >> 16);
    float fh = __uint_as_float((unsigned)hi << 16);
    float fl = f - fh;
    unsigned ul = __float_as_uint(fl);
    unsigned rl = ul + 0x7FFFu + ((ul >> 16) & 1u);
    lo = (unsigned short)(rl >> 16);
}

// ---------------------------------------------------------------------------
// split_x: x fp32 (16384x1024) -> XH, XL bf16 (in d_out scratch)
// ---------------------------------------------------------------------------
__global__ __launch_bounds__(256) void split_x_kernel(
    const float* __restrict__ x, unsigned short* __restrict__ XH,
    unsigned short* __restrict__ XL)
{
    int i = blockIdx.x * 256 + threadIdx.x;    // x4 floats
    float4 v = ((const float4*)x)[i];
    ushort4 h, l;
    bf16_split(v.x, h.x, l.x);
    bf16_split(v.y, h.y, l.y);
    bf16_split(v.z, h.z, l.z);
    bf16_split(v.w, h.w, l.w);
    ((ushort4*)XH)[i] = h;
    ((ushort4*)XL)[i] = l;
}

// ---------------------------------------------------------------------------
// split_w: [Wproj;Wphase] fp32 (1792x1024) -> WH, WL bf16
// ---------------------------------------------------------------------------
__global__ __launch_bounds__(256) void split_w_kernel(
    const float* __restrict__ Wproj, const float* __restrict__ Wphase,
    unsigned short* __restrict__ WH, unsigned short* __restrict__ WL)
{
    int i = blockIdx.x * 256 + threadIdx.x;    // x4 floats
    int elem = i << 2;
    int row = elem >> 10;
    int col = elem & 1023;
    const float* src = (row < 1536) ? (Wproj + (size_t)row * 1024 + col)
                                    : (Wphase + (size_t)(row - 1536) * 1024 + col);
    float4 v = *(const float4*)src;
    ushort4 h, l;
    bf16_split(v.x, h.x, l.x);
    bf16_split(v.y, h.y, l.y);
    bf16_split(v.z, h.z, l.z);
    bf16_split(v.w, h.w, l.w);
    ((ushort4*)WH)[i] = h;
    ((ushort4*)WL)[i] = l;
}

// ---------------------------------------------------------------------------
// pack_wres: W_res fp32 (1024 x 1022) -> WPH bf16 (1024 x 1024), padded 0
// ---------------------------------------------------------------------------
__global__ __launch_bounds__(256) void pack_wres_kernel(
    const float* __restrict__ Wres, unsigned short* __restrict__ WPH)
{
    int idx = blockIdx.x * 256 + threadIdx.x;   // 0 .. 1024*1024-1
    int d = idx >> 10;
    int j = idx & 1023;
    float v = (j < 1022) ? Wres[(size_t)d * 1022 + j] : 0.0f;
    unsigned u = __float_as_uint(v);
    unsigned r = u + 0x7FFFu + ((u >> 16) & 1u);
    WPH[idx] = (unsigned short)(r >> 16);
}

// ---------------------------------------------------------------------------
// GEMM1-full (3-term split-bf16): PT rows 256..767 (omega, phi) — these feed
// the oscillator angle (amplified by log-position <= 8.3) and need ~fp32.
//   jt = blockIdx.y + 2
// (round-2 proven structure)
// ---------------------------------------------------------------------------
__global__ __launch_bounds__(256, 3) void gemm1_full_kernel(
    const unsigned short* __restrict__ WH, const unsigned short* __restrict__ WL,
    const unsigned short* __restrict__ XH, const unsigned short* __restrict__ XL,
    const float* __restrict__ bproj, float* __restrict__ PT)
{
    __shared__ __attribute__((aligned(16))) unsigned short AH[4096];
    __shared__ __attribute__((aligned(16))) unsigned short AL[4096];
    __shared__ __attribute__((aligned(16))) unsigned short BH[4096];
    __shared__ __attribute__((aligned(16))) unsigned short BL[4096];

    const int tid  = threadIdx.x;
    const int lane = tid & 63;
    const int w    = tid >> 6;          // wave 0..3
    const int wm   = w >> 1, wn = w & 1;
    const int m0   = (blockIdx.y + 2) * 128;  // j tile (rows 256..767)
    const int n0   = blockIdx.x * 128;        // r tile
    const int fr   = lane & 15;
    const int fq   = lane >> 4;         // 0..3

    f32x4 acc[4][4];
    #pragma unroll
    for (int i = 0; i < 4; i++)
        #pragma unroll
        for (int j = 0; j < 4; j++) acc[i][j] = (f32x4){0.f, 0.f, 0.f, 0.f};

    for (int kc = 0; kc < 32; kc++) {
        const int kbase = kc * 32;
        __syncthreads();
        #pragma unroll
        for (int t = 0; t < 2; t++) {
            int G  = w * 128 + t * 64 + lane;       // granule index 0..511
            int gm = G & 127;
            int gq = G >> 7;
            size_t offA = (size_t)(m0 + gm) * 1024 + kbase + gq * 8;
            size_t offB = (size_t)(n0 + gm) * 1024 + kbase + gq * 8;
            int ldsg = (w * 128 + t * 64) * 8;      // wave-uniform base (shorts)
            GL2LDS(WH + offA, &AH[ldsg]);
            GL2LDS(WL + offA, &AL[ldsg]);
            GL2LDS(XH + offB, &BH[ldsg]);
            GL2LDS(XL + offB, &BL[ldsg]);
        }
        __syncthreads();

        s16x8 ah[4], al[4], bh[4], bl[4];
        #pragma unroll
        for (int f = 0; f < 4; f++) {
            int aoff = (fq * 128 + wm * 64 + f * 16 + fr) * 8;
            int boff = (fq * 128 + wn * 64 + f * 16 + fr) * 8;
            ah[f] = *(const s16x8*)&AH[aoff];
            al[f] = *(const s16x8*)&AL[aoff];
            bh[f] = *(const s16x8*)&BH[boff];
            bl[f] = *(const s16x8*)&BL[boff];
        }
        #pragma unroll
        for (int i = 0; i < 4; i++)
            #pragma unroll
            for (int j = 0; j < 4; j++) {
                acc[i][j] = __builtin_amdgcn_mfma_f32_16x16x32_bf16(ah[i], bh[j], acc[i][j], 0, 0, 0);
                acc[i][j] = __builtin_amdgcn_mfma_f32_16x16x32_bf16(ah[i], bl[j], acc[i][j], 0, 0, 0);
                acc[i][j] = __builtin_amdgcn_mfma_f32_16x16x32_bf16(al[i], bh[j], acc[i][j], 0, 0, 0);
            }
    }

    #pragma unroll
    for (int i = 0; i < 4; i++) {
        int mbase = m0 + wm * 64 + i * 16 + fq * 4;
        #pragma unroll
        for (int j = 0; j < 4; j++) {
            int n = n0 + wn * 64 + j * 16 + fr;
            #pragma unroll
            for (int rg = 0; rg < 4; rg++) {
                int m = mbase + rg;
                PT[(size_t)m * NROW + n] = acc[i][j][rg] + bproj[m];
            }
        }
    }
}

// ---------------------------------------------------------------------------
// GEMM1-lite (single bf16): PT rows 0..255, 768..1791. BK=64 (round-2 proven).
//   jt = (blockIdx.y < 2) ? blockIdx.y : blockIdx.y + 4
// ---------------------------------------------------------------------------
__global__ __launch_bounds__(256, 4) void gemm1_lite_kernel(
    const unsigned short* __restrict__ WH, const unsigned short* __restrict__ XH,
    const float* __restrict__ bproj, const float* __restrict__ bphase,
    float* __restrict__ PT)
{
    __shared__ __attribute__((aligned(16))) unsigned short AH[8192]; // 128x64
    __shared__ __attribute__((aligned(16))) unsigned short BH[8192];

    const int tid  = threadIdx.x;
    const int lane = tid & 63;
    const int w    = tid >> 6;
    const int wm   = w >> 1, wn = w & 1;
    const int yt   = blockIdx.y;
    const int jt   = (yt < 2) ? yt : yt + 4;
    const int m0   = jt * 128;
    const int n0   = blockIdx.x * 128;
    const int fr   = lane & 15;
    const int fq   = lane >> 4;

    f32x4 acc[4][4];
    #pragma unroll
    for (int i = 0; i < 4; i++)
        #pragma unroll
        for (int j = 0; j < 4; j++) acc[i][j] = (f32x4){0.f, 0.f, 0.f, 0.f};

    for (int kc = 0; kc < 16; kc++) {
        const int kbase = kc * 64;
        __syncthreads();
        #pragma unroll
        for (int t = 0; t < 4; t++) {
            int G  = t * 256 + tid;                 // granule index 0..1023
            int gm = G & 127;
            int gq = G >> 7;                        // ksub 0..7
            size_t offA = (size_t)(m0 + gm) * 1024 + kbase + gq * 8;
            size_t offB = (size_t)(n0 + gm) * 1024 + kbase + gq * 8;
            int ldsg = (t * 256 + w * 64) * 8;      // wave-uniform base (shorts)
            GL2LDS(WH + offA, &AH[ldsg]);
            GL2LDS(XH + offB, &BH[ldsg]);
        }
        __syncthreads();

        #pragma unroll
        for (int s = 0; s < 2; s++) {
            s16x8 ah[4], bh[4];
            #pragma unroll
            for (int f = 0; f < 4; f++) {
                int aoff = (((s * 4 + fq) * 128) + wm * 64 + f * 16 + fr) * 8;
                int boff = (((s * 4 + fq) * 128) + wn * 64 + f * 16 + fr) * 8;
                ah[f] = *(const s16x8*)&AH[aoff];
                bh[f] = *(const s16x8*)&BH[boff];
            }
            #pragma unroll
            for (int i = 0; i < 4; i++)
                #pragma unroll
                for (int j = 0; j < 4; j++)
                    acc[i][j] = __builtin_amdgcn_mfma_f32_16x16x32_bf16(ah[i], bh[j], acc[i][j], 0, 0, 0);
        }
    }

    #pragma unroll
    for (int i = 0; i < 4; i++) {
        int mbase = m0 + wm * 64 + i * 16 + fq * 4;
        #pragma unroll
        for (int j = 0; j < 4; j++) {
            int n = n0 + wn * 64 + j * 16 + fr;
            #pragma unroll
            for (int rg = 0; rg < 4; rg++) {
                int m = mbase + rg;
                float bias = (m < 1536) ? bproj[m] : bphase[m - 1536];
                PT[(size_t)m * NROW + n] = acc[i][j][rg] + bias;
            }
        }
    }
}

// ---------------------------------------------------------------------------
// Scan kernel v3: v1's coalesced memory pattern + v2's shfl-based block scan.
//  * pass 1/3 global access: n = i*256 + t (perfectly coalesced, per-element)
//  * alpha/drive staged in LDS at pidx = n + (n>>4); chunk reads at stride 17
//    (17 coprime 32 -> conflict-free)
//  * block scan: intra-wave Kogge-Stone via __shfl_up + 48B wave-aggregate
//    exchange -> 3 barriers total (v1 had 18)
//  * LDS 52.3KB (< 160/3) -> 3 blocks/CU (v1: 55296B -> 2 blocks/CU)
//  * cs/sn carried in registers between pass 1 and pass 3
// ---------------------------------------------------------------------------
__global__ __launch_bounds__(256, 3) void scan_kernel(float* PT,
                                                      const float* lambda_ptr)
{
    const int bx = blockIdx.x;         // 0..1023
    const int k = bx & 255;
    const int b = bx >> 8;
    const int t = threadIdx.x;         // 0..255
    const int lane = t & 63;
    const int wv = t >> 6;             // 0..3
    const size_t colb = (size_t)b * NSEQ;
    const size_t R = NROW;

    float* rowA  = PT + (size_t)(k)        * R + colb;  // a_raw -> rho_re
    float* rowW  = PT + (size_t)(256 + k)  * R + colb;  // w_raw -> rho_im
    float* rowP  = PT + (size_t)(512 + k)  * R + colb;  // p_raw -> g
    float* rowAl = PT + (size_t)(768 + k)  * R + colb;  // al_raw
    float* rowG  = PT + (size_t)(1024 + k) * R + colb;  // g_raw
    float* rowBe = PT + (size_t)(1280 + k) * R + colb;  // be_raw
    float* rowPq = PT + (size_t)(1536 + k) * R + colb;  // phase query

    __shared__ float s_al[NSEQ + 256];
    __shared__ float s_rr[NSEQ + 256];
    __shared__ float s_ri[NSEQ + 256];
    __shared__ float s_wa[4], s_wbr[4], s_wbi[4];

    const float lam = *lambda_ptr;

    float cs_r[16], sn_r[16];          // fully unrolled -> stays in VGPRs

    // ---- pass 1: coalesced loads; compute alpha/drive/cos/sin; stage to LDS
    #pragma unroll
    for (int i = 0; i < 16; i++) {
        int n = i * 256 + t;
        float araw = rowA[n];
        float wraw = rowW[n];
        float praw = rowP[n];
        float alraw = rowAl[n];
        float A     = 3.0f * sigm(araw);
        float alpha = sigm(alraw);
        float omega = softplusf_(wraw);
        float ang   = fmaf(omega, log1pf((float)n), praw);
        float sn, cs;
        sincosf(ang, &sn, &cs);
        cs_r[i] = cs;
        sn_r[i] = sn;
        float amp = (1.0f - alpha) * A;
        int pidx = n + (n >> 4);
        s_al[pidx] = alpha;
        s_rr[pidx] = amp * cs;
        s_ri[pidx] = amp * sn;
    }
    __syncthreads();

    // ---- per-thread serial over its 16-chunk (LDS stride-17 reads)
    float ap = 1.0f, br = 0.0f, bi = 0.0f;
    {
        int base = t * 17;
        #pragma unroll
        for (int i = 0; i < 16; i++) {
            float a = s_al[base + i];
            br = fmaf(a, br, s_rr[base + i]);
            bi = fmaf(a, bi, s_ri[base + i]);
            ap *= a;
        }
    }

    // ---- intra-wave inclusive Kogge-Stone scan of (ap, br, bi)
    #pragma unroll
    for (int off = 1; off < 64; off <<= 1) {
        float pa  = __shfl_up(ap, off);
        float pbr = __shfl_up(br, off);
        float pbi = __shfl_up(bi, off);
        if (lane >= off) {
            br = fmaf(ap, pbr, br);     // B = A_self*B_prev + B_self
            bi = fmaf(ap, pbi, bi);
            ap *= pa;
        }
    }

    // ---- cross-wave composition via 48B LDS
    if (lane == 63) { s_wa[wv] = ap; s_wbr[wv] = br; s_wbi[wv] = bi; }
    __syncthreads();
    float cbr = 0.0f, cbi = 0.0f;       // fold waves 0..wv-1 (left to right)
    #pragma unroll
    for (int u = 0; u < 3; u++) {
        if (u < wv) {
            cbr = fmaf(s_wa[u], cbr, s_wbr[u]);
            cbi = fmaf(s_wa[u], cbi, s_wbi[u]);
        }
    }
    // exclusive intra-wave prefix
    float ea  = __shfl_up(ap, 1);
    float ebr = __shfl_up(br, 1);
    float ebi = __shfl_up(bi, 1);
    if (lane == 0) { ea = 1.0f; ebr = 0.0f; ebi = 0.0f; }
    float cr = fmaf(ea, cbr, ebr);      // r at chunk start - 1
    float ci = fmaf(ea, cbi, ebi);

    // ---- local prefix completion (write scan results back to LDS)
    {
        int base = t * 17;
        #pragma unroll
        for (int i = 0; i < 16; i++) {
            float a = s_al[base + i];
            cr = fmaf(a, cr, s_rr[base + i]);
            ci = fmaf(a, ci, s_ri[base + i]);
            s_rr[base + i] = cr;
            s_ri[base + i] = ci;
        }
    }
    __syncthreads();

    // ---- pass 3: coalesced; erase, norm, demodulate, gate; write outputs
    #pragma unroll
    for (int i = 0; i < 16; i++) {
        int n = i * 256 + t;
        float beraw = rowBe[n];
        float graw = rowG[n];
        float pq = rowPq[n];

        float cs = cs_r[i];
        float sn = sn_r[i];

        int pidx = n + (n >> 4);
        float rr = s_rr[pidx], ri = s_ri[pidx];
        float beta = sigm(beraw);
        float g = sigm(graw);

        float readout = rr * cs + ri * sn;
        rr -= beta * readout * cs;
        ri -= beta * readout * sn;

        float modulus = sqrtf(rr * rr + ri * ri + 1e-8f);
        float scale = fmaxf(modulus, 1.0f);
        rr /= scale; ri /= scale;

        float rho_re = rr * cs + ri * sn;
        float rho_im = -rr * sn + ri * cs;

        float rho_norm = sqrtf(rho_re * rho_re + rho_im * rho_im + 1e-8f);
        float sq, cq;
        sincosf(pq, &sq, &cq);
        float pa = (rho_re * cq + rho_im * sq) / rho_norm;
        float gate = sigm(lam * pa);
        rho_re *= gate;
        rho_im *= gate;

        rowA[n] = rho_re;
        rowW[n] = rho_im;
        rowP[n] = g;
    }
}

// ---------------------------------------------------------------------------
// pack_rho: fused cross-products + transpose + bf16 split.
// ---------------------------------------------------------------------------
__global__ __launch_bounds__(256) void pack_rho_kernel(
    const float* __restrict__ PT, unsigned short* __restrict__ RTH,
    unsigned short* __restrict__ RTL)
{
    __shared__ float s_re[256 * 33];
    __shared__ float s_im[256 * 33];
    __shared__ float s_g [256 * 33];

    const int tid = threadIdx.x;
    const int r0 = blockIdx.x * 32;

    {
        int lr = tid & 31;
        int k0 = tid >> 5;       // 0..7
        for (int it = 0; it < 32; it++) {
            int k = it * 8 + k0;
            size_t go = (size_t)k * NROW + r0 + lr;
            s_re[k * 33 + lr] = PT[go];
            s_im[k * 33 + lr] = PT[(size_t)256 * NROW + go];
            s_g [k * 33 + lr] = PT[(size_t)512 * NROW + go];
        }
    }
    __syncthreads();

    const int r = tid >> 3;      // 0..31
    const int c = tid & 7;       // 0..7
    for (int i = 0; i < 16; i++) {
        int jb = (c + 8 * i) * 8;       // 0..1016, step 8
        unsigned short h[8], l[8];
        #pragma unroll
        for (int e = 0; e < 8; e++) {
            int j = jb + e;
            float v;
            if (j < 256) {
                v = s_g[j * 33 + r] * s_re[j * 33 + r];
            } else if (j < 512) {
                int k = j - 256;
                v = s_g[k * 33 + r] * s_im[k * 33 + r];
            } else if (j < 767) {
                int k = j - 512;
                float gc = 0.5f * (s_g[k * 33 + r] + s_g[(k + 1) * 33 + r]);
                v = gc * (s_re[k * 33 + r] * s_re[(k + 1) * 33 + r]
                        - s_im[k * 33 + r] * s_im[(k + 1) * 33 + r]);
            } else if (j < 1022) {
                int k = j - 767;
                float gc = 0.5f * (s_g[k * 33 + r] + s_g[(k + 1) * 33 + r]);
                v = gc * (s_re[k * 33 + r] * s_im[(k + 1) * 33 + r]
                        + s_im[k * 33 + r] * s_re[(k + 1) * 33 + r]);
            } else {
                v = 0.0f;
            }
            bf16_split(v, h[e], l[e]);
        }
        size_t off = (size_t)(r0 + r) * 1024 + jb;
        s16x8 hv, lv;
        #pragma unroll
        for (int e = 0; e < 8; e++) { hv[e] = (short)h[e]; lv[e] = (short)l[e]; }
        *(s16x8*)&RTH[off] = hv;
        *(s16x8*)&RTL[off] = lv;
    }
}

// ---------------------------------------------------------------------------
// GEMM2 (2-term: W_res bf16, rho hi+lo): out[r,d] = rs * sum_j RT[r,j]*WP[d,j]
// (round-2 proven structure)
// ---------------------------------------------------------------------------
__global__ __launch_bounds__(256, 3) void gemm2_kernel(
    const unsigned short* __restrict__ WPH,
    const unsigned short* __restrict__ RTH, const unsigned short* __restrict__ RTL,
    const float* __restrict__ rs_ptr, float* __restrict__ out)
{
    __shared__ __attribute__((aligned(16))) unsigned short AH[4096];
    __shared__ __attribute__((aligned(16))) unsigned short BH[4096];
    __shared__ __attribute__((aligned(16))) unsigned short BL[4096];

    const int tid  = threadIdx.x;
    const int lane = tid & 63;
    const int w    = tid >> 6;
    const int wm   = w >> 1, wn = w & 1;
    const int m0   = blockIdx.y * 128;  // d tile
    const int n0   = blockIdx.x * 128;  // r tile
    const int fr   = lane & 15;
    const int fq   = lane >> 4;
    const float rs = *rs_ptr;

    f32x4 acc[4][4];
    #pragma unroll
    for (int i = 0; i < 4; i++)
        #pragma unroll
        for (int j = 0; j < 4; j++) acc[i][j] = (f32x4){0.f, 0.f, 0.f, 0.f};

    for (int kc = 0; kc < 32; kc++) {
        const int kbase = kc * 32;
        __syncthreads();
        #pragma unroll
        for (int t = 0; t < 2; t++) {
            int G  = w * 128 + t * 64 + lane;
            int gm = G & 127;
            int gq = G >> 7;
            size_t offA = (size_t)(m0 + gm) * 1024 + kbase + gq * 8;
            size_t offB = (size_t)(n0 + gm) * 1024 + kbase + gq * 8;
            int ldsg = (w * 128 + t * 64) * 8;
            GL2LDS(WPH + offA, &AH[ldsg]);
            GL2LDS(RTH + offB, &BH[ldsg]);
            GL2LDS(RTL + offB, &BL[ldsg]);
        }
        __syncthreads();

        s16x8 ah[4], bh[4], bl[4];
        #pragma unroll
        for (int f = 0; f < 4; f++) {
            int aoff = (fq * 128 + wm * 64 + f * 16 + fr) * 8;
            int boff = (fq * 128 + wn * 64 + f * 16 + fr) * 8;
            ah[f] = *(const s16x8*)&AH[aoff];
            bh[f] = *(const s16x8*)&BH[boff];
            bl[f] = *(const s16x8*)&BL[boff];
        }
        #pragma unroll
        for (int i = 0; i < 4; i++)
            #pragma unroll
            for (int j = 0; j < 4; j++) {
                acc[i][j] = __builtin_amdgcn_mfma_f32_16x16x32_bf16(ah[i], bh[j], acc[i][j], 0, 0, 0);
                acc[i][j] = __builtin_amdgcn_mfma_f32_16x16x32_bf16(ah[i], bl[j], acc[i][j], 0, 0, 0);
            }
    }

    #pragma unroll
    for (int i = 0; i < 4; i++) {
        int d = m0 + wm * 64 + i * 16 + fq * 4;
        #pragma unroll
        for (int j = 0; j < 4; j++) {
            int n = n0 + wn * 64 + j * 16 + fr;
            float4 v = { rs * acc[i][j][0], rs * acc[i][j][1],
                         rs * acc[i][j][2], rs * acc[i][j][3] };
            *(float4*)&out[(size_t)n * 1024 + d] = v;
        }
    }
}

// ---------------------------------------------------------------------------
extern "C" void kernel_launch(void* const* d_in, const int* in_sizes, int n_in,
                              void* d_out, int out_size, void* d_ws, size_t ws_size,
                              hipStream_t stream)
{
    const float* x      = (const float*)d_in[0];
    const float* Wproj  = (const float*)d_in[1];
    const float* bproj  = (const float*)d_in[2];
    const float* Wres   = (const float*)d_in[3];
    const float* Wphase = (const float*)d_in[4];
    const float* bphase = (const float*)d_in[5];
    const float* lam    = (const float*)d_in[6];
    const float* rs     = (const float*)d_in[7];
    float* out = (float*)d_out;

    // workspace layout (~124.8 MB):
    //   PT fp32 [1792][16384]           (117.4 MB)
    //   WH, WL bf16 [1792][1024]        (7.3 MB, after PT)
    // aliased into dead PT rows:
    //   RTH bf16 [16384][1024] = PT rows  768..1279
    //   RTL bf16 [16384][1024] = PT rows 1280..1791
    //   WPH bf16 [1024][1024]  = PT rows 0..31 (after pack_rho)
    // d_out doubles as XH/XL bf16 scratch until gemm2 overwrites it.
    float* PT = (float*)d_ws;
    unsigned short* WH  = (unsigned short*)((char*)d_ws + (size_t)JTOT * NROW * 4);
    unsigned short* WL  = WH + (size_t)JTOT * 1024;
    unsigned short* RTH = (unsigned short*)(PT + (size_t)768 * NROW);
    unsigned short* RTL = RTH + (size_t)NROW * 1024;
    unsigned short* WPH = (unsigned short*)PT;
    unsigned short* XH  = (unsigned short*)d_out;
    unsigned short* XL  = XH + (size_t)NROW * 1024;

    hipLaunchKernelGGL(split_x_kernel, dim3(NROW * D_MODEL / 1024), dim3(256), 0, stream,
                       x, XH, XL);
    hipLaunchKernelGGL(split_w_kernel, dim3(JTOT * D_MODEL / 1024), dim3(256), 0, stream,
                       Wproj, Wphase, WH, WL);
    hipLaunchKernelGGL(gemm1_full_kernel, dim3(NROW / 128, 4), dim3(256), 0, stream,
                       WH, WL, XH, XL, bproj, PT);
    hipLaunchKernelGGL(gemm1_lite_kernel, dim3(NROW / 128, 10), dim3(256), 0, stream,
                       WH, XH, bproj, bphase, PT);
    hipLaunchKernelGGL(scan_kernel, dim3(BATCH * KOSC), dim3(256), 0, stream,
                       PT, lam);
    hipLaunchKernelGGL(pack_rho_kernel, dim3(NROW / 32), dim3(256), 0, stream,
                       PT, RTH, RTL);
    hipLaunchKernelGGL(pack_wres_kernel, dim3(1024 * 1024 / 256), dim3(256), 0, stream,
                       Wres, WPH);
    hipLaunchKernelGGL(gemm2_kernel, dim3(NROW / 128, 1024 / 128), dim3(256), 0, stream,
                       WPH, RTH, RTL, rs, out);
}

// Round 8
// 526.305 us; speedup vs baseline: 1.3424x; 1.0248x over previous
//
#include <hip/hip_runtime.h>
#include <cmath>

// Problem constants
#define D_MODEL 1024
#define KOSC    256
#define NSEQ    4096
#define BATCH   4
#define NROW    (BATCH * NSEQ)   // 16384 rows (b*n)
#define JTOT    1792             // 6K proj + K phase

typedef short      s16x8 __attribute__((ext_vector_type(8)));
typedef float      f32x4 __attribute__((ext_vector_type(4)));

// async global->LDS, 16B per lane; LDS dest = wave-uniform base + lane*16
#define GL2LDS(gsrc, ldst)                                                      \
  __builtin_amdgcn_global_load_lds(                                             \
      (const __attribute__((address_space(1))) unsigned int*)(gsrc),            \
      (__attribute__((address_space(3))) unsigned int*)(ldst), 16, 0, 0)

__device__ __forceinline__ float sigm(float x) {
    return 1.0f / (1.0f + expf(-x));
}
__device__ __forceinline__ float softplusf_(float x) {
    return fmaxf(x, 0.0f) + log1pf(expf(-fabsf(x)));
}

// round-to-nearest-even bf16 split: f = hi + lo, residual ~2^-18 * |f|
__device__ __forceinline__ void bf16_split(float f, unsigned short& hi,
                                           unsigned short& lo) {
    unsigned u = __float_as_uint(f);
    unsigned r = u + 0x7FFFu + ((u >> 16) & 1u);
    hi = (unsigned short)(r >> 16);
    float fh = __uint_as_float((unsigned)hi << 16);
    float fl = f - fh;
    unsigned ul = __float_as_uint(fl);
    unsigned rl = ul + 0x7FFFu + ((ul >> 16) & 1u);
    lo = (unsigned short)(rl >> 16);
}

// ---------------------------------------------------------------------------
// split_x: x fp32 (16384x1024) -> XH, XL bf16 (in d_out scratch)
// ---------------------------------------------------------------------------
__global__ __launch_bounds__(256) void split_x_kernel(
    const float* __restrict__ x, unsigned short* __restrict__ XH,
    unsigned short* __restrict__ XL)
{
    int i = blockIdx.x * 256 + threadIdx.x;    // x4 floats
    float4 v = ((const float4*)x)[i];
    ushort4 h, l;
    bf16_split(v.x, h.x, l.x);
    bf16_split(v.y, h.y, l.y);
    bf16_split(v.z, h.z, l.z);
    bf16_split(v.w, h.w, l.w);
    ((ushort4*)XH)[i] = h;
    ((ushort4*)XL)[i] = l;
}

// ---------------------------------------------------------------------------
// split_w: [Wproj;Wphase] fp32 (1792x1024) -> WH, WL bf16
// ---------------------------------------------------------------------------
__global__ __launch_bounds__(256) void split_w_kernel(
    const float* __restrict__ Wproj, const float* __restrict__ Wphase,
    unsigned short* __restrict__ WH, unsigned short* __restrict__ WL)
{
    int i = blockIdx.x * 256 + threadIdx.x;    // x4 floats
    int elem = i << 2;
    int row = elem >> 10;
    int col = elem & 1023;
    const float* src = (row < 1536) ? (Wproj + (size_t)row * 1024 + col)
                                    : (Wphase + (size_t)(row - 1536) * 1024 + col);
    float4 v = *(const float4*)src;
    ushort4 h, l;
    bf16_split(v.x, h.x, l.x);
    bf16_split(v.y, h.y, l.y);
    bf16_split(v.z, h.z, l.z);
    bf16_split(v.w, h.w, l.w);
    ((ushort4*)WH)[i] = h;
    ((ushort4*)WL)[i] = l;
}

// ---------------------------------------------------------------------------
// pack_wres: W_res fp32 (1024 x 1022) -> WPH bf16 (1024 x 1024), padded 0
// ---------------------------------------------------------------------------
__global__ __launch_bounds__(256) void pack_wres_kernel(
    const float* __restrict__ Wres, unsigned short* __restrict__ WPH)
{
    int idx = blockIdx.x * 256 + threadIdx.x;   // 0 .. 1024*1024-1
    int d = idx >> 10;
    int j = idx & 1023;
    float v = (j < 1022) ? Wres[(size_t)d * 1022 + j] : 0.0f;
    unsigned u = __float_as_uint(v);
    unsigned r = u + 0x7FFFu + ((u >> 16) & 1u);
    WPH[idx] = (unsigned short)(r >> 16);
}

// ---------------------------------------------------------------------------
// GEMM1-full (3-term split-bf16): PT rows 256..767 (omega, phi) — these feed
// the oscillator angle (amplified by log-position <= 8.3) and need ~fp32.
//   jt = blockIdx.y + 2
// (round-2 proven structure; LDS ratio 0.62 — already the best of the three)
// ---------------------------------------------------------------------------
__global__ __launch_bounds__(256, 3) void gemm1_full_kernel(
    const unsigned short* __restrict__ WH, const unsigned short* __restrict__ WL,
    const unsigned short* __restrict__ XH, const unsigned short* __restrict__ XL,
    const float* __restrict__ bproj, float* __restrict__ PT)
{
    __shared__ __attribute__((aligned(16))) unsigned short AH[4096];
    __shared__ __attribute__((aligned(16))) unsigned short AL[4096];
    __shared__ __attribute__((aligned(16))) unsigned short BH[4096];
    __shared__ __attribute__((aligned(16))) unsigned short BL[4096];

    const int tid  = threadIdx.x;
    const int lane = tid & 63;
    const int w    = tid >> 6;          // wave 0..3
    const int wm   = w >> 1, wn = w & 1;
    const int m0   = (blockIdx.y + 2) * 128;  // j tile (rows 256..767)
    const int n0   = blockIdx.x * 128;        // r tile
    const int fr   = lane & 15;
    const int fq   = lane >> 4;         // 0..3

    f32x4 acc[4][4];
    #pragma unroll
    for (int i = 0; i < 4; i++)
        #pragma unroll
        for (int j = 0; j < 4; j++) acc[i][j] = (f32x4){0.f, 0.f, 0.f, 0.f};

    for (int kc = 0; kc < 32; kc++) {
        const int kbase = kc * 32;
        __syncthreads();
        #pragma unroll
        for (int t = 0; t < 2; t++) {
            int G  = w * 128 + t * 64 + lane;       // granule index 0..511
            int gm = G & 127;
            int gq = G >> 7;
            size_t offA = (size_t)(m0 + gm) * 1024 + kbase + gq * 8;
            size_t offB = (size_t)(n0 + gm) * 1024 + kbase + gq * 8;
            int ldsg = (w * 128 + t * 64) * 8;      // wave-uniform base (shorts)
            GL2LDS(WH + offA, &AH[ldsg]);
            GL2LDS(WL + offA, &AL[ldsg]);
            GL2LDS(XH + offB, &BH[ldsg]);
            GL2LDS(XL + offB, &BL[ldsg]);
        }
        __syncthreads();

        s16x8 ah[4], al[4], bh[4], bl[4];
        #pragma unroll
        for (int f = 0; f < 4; f++) {
            int aoff = (fq * 128 + wm * 64 + f * 16 + fr) * 8;
            int boff = (fq * 128 + wn * 64 + f * 16 + fr) * 8;
            ah[f] = *(const s16x8*)&AH[aoff];
            al[f] = *(const s16x8*)&AL[aoff];
            bh[f] = *(const s16x8*)&BH[boff];
            bl[f] = *(const s16x8*)&BL[boff];
        }
        #pragma unroll
        for (int i = 0; i < 4; i++)
            #pragma unroll
            for (int j = 0; j < 4; j++) {
                acc[i][j] = __builtin_amdgcn_mfma_f32_16x16x32_bf16(ah[i], bh[j], acc[i][j], 0, 0, 0);
                acc[i][j] = __builtin_amdgcn_mfma_f32_16x16x32_bf16(ah[i], bl[j], acc[i][j], 0, 0, 0);
                acc[i][j] = __builtin_amdgcn_mfma_f32_16x16x32_bf16(al[i], bh[j], acc[i][j], 0, 0, 0);
            }
    }

    #pragma unroll
    for (int i = 0; i < 4; i++) {
        int mbase = m0 + wm * 64 + i * 16 + fq * 4;
        #pragma unroll
        for (int j = 0; j < 4; j++) {
            int n = n0 + wn * 64 + j * 16 + fr;
            #pragma unroll
            for (int rg = 0; rg < 4; rg++) {
                int m = mbase + rg;
                PT[(size_t)m * NROW + n] = acc[i][j][rg] + bproj[m];
            }
        }
    }
}

// ---------------------------------------------------------------------------
// GEMM1-lite (single bf16): PT rows 0..255, 768..1791.
// Wave tile 128x64 (acc 8x4), block 256j x 128r — halves LDS bytes/MFMA vs
// the 64x64 wave tile. Same 2-barrier skeleton. K-order unchanged.
//   m0: yt=0 -> rows 0..255; yt=1..4 -> rows 768..1791
// ---------------------------------------------------------------------------
__global__ __launch_bounds__(256, 2) void gemm1_lite_kernel(
    const unsigned short* __restrict__ WH, const unsigned short* __restrict__ XH,
    const float* __restrict__ bproj, const float* __restrict__ bphase,
    float* __restrict__ PT)
{
    __shared__ __attribute__((aligned(16))) unsigned short AH[8192]; // 256x32
    __shared__ __attribute__((aligned(16))) unsigned short BH[4096]; // 128x32

    const int tid  = threadIdx.x;
    const int lane = tid & 63;
    const int w    = tid >> 6;
    const int wm   = w >> 1;            // 0..1: j half (128)
    const int wn   = w & 1;             // 0..1: r half (64)
    const int yt   = blockIdx.y;        // 0..4
    const int m0   = (yt == 0) ? 0 : (512 + yt * 256);  // 0,768,1024,1280,1536
    const int n0   = blockIdx.x * 128;
    const int fr   = lane & 15;
    const int fq   = lane >> 4;

    f32x4 acc[8][4];
    #pragma unroll
    for (int i = 0; i < 8; i++)
        #pragma unroll
        for (int j = 0; j < 4; j++) acc[i][j] = (f32x4){0.f, 0.f, 0.f, 0.f};

    for (int kc = 0; kc < 32; kc++) {
        const int kbase = kc * 32;
        __syncthreads();
        // A: 1024 granules (256 rows x 4 ksubs)
        #pragma unroll
        for (int it = 0; it < 4; it++) {
            int G   = it * 256 + tid;
            int row = G & 255;
            int gq  = G >> 8;
            size_t offA = (size_t)(m0 + row) * 1024 + kbase + gq * 8;
            int ldsg = (it * 256 + w * 64) * 8;     // wave-uniform base
            GL2LDS(WH + offA, &AH[ldsg]);
        }
        // B: 512 granules (128 rows x 4 ksubs)
        #pragma unroll
        for (int it = 0; it < 2; it++) {
            int G   = it * 256 + tid;
            int row = G & 127;
            int gq  = G >> 7;
            size_t offB = (size_t)(n0 + row) * 1024 + kbase + gq * 8;
            int ldsg = (it * 256 + w * 64) * 8;
            GL2LDS(XH + offB, &BH[ldsg]);
        }
        __syncthreads();

        s16x8 ah[8], bh[4];
        #pragma unroll
        for (int i = 0; i < 8; i++)
            ah[i] = *(const s16x8*)&AH[(fq * 256 + wm * 128 + i * 16 + fr) * 8];
        #pragma unroll
        for (int j = 0; j < 4; j++)
            bh[j] = *(const s16x8*)&BH[(fq * 128 + wn * 64 + j * 16 + fr) * 8];
        #pragma unroll
        for (int i = 0; i < 8; i++)
            #pragma unroll
            for (int j = 0; j < 4; j++)
                acc[i][j] = __builtin_amdgcn_mfma_f32_16x16x32_bf16(ah[i], bh[j], acc[i][j], 0, 0, 0);
    }

    #pragma unroll
    for (int i = 0; i < 8; i++) {
        int mbase = m0 + wm * 128 + i * 16 + fq * 4;
        #pragma unroll
        for (int j = 0; j < 4; j++) {
            int n = n0 + wn * 64 + j * 16 + fr;
            #pragma unroll
            for (int rg = 0; rg < 4; rg++) {
                int m = mbase + rg;
                float bias = (m < 1536) ? bproj[m] : bphase[m - 1536];
                PT[(size_t)m * NROW + n] = acc[i][j][rg] + bias;
            }
        }
    }
}

// ---------------------------------------------------------------------------
// Scan kernel (round-2 proven): one block per (b, k) channel. cs/sn carried
// in registers between pass 1 and pass 3.
// ---------------------------------------------------------------------------
__global__ __launch_bounds__(256) void scan_kernel(float* PT,
                                                   const float* lambda_ptr)
{
    const int bx = blockIdx.x;         // 0..1023
    const int k = bx & 255;
    const int b = bx >> 8;
    const int t = threadIdx.x;         // 0..255
    const size_t colb = (size_t)b * NSEQ;
    const size_t R = NROW;

    float* rowA  = PT + (size_t)(k)        * R + colb;  // a_raw -> rho_re
    float* rowW  = PT + (size_t)(256 + k)  * R + colb;  // w_raw -> rho_im
    float* rowP  = PT + (size_t)(512 + k)  * R + colb;  // p_raw -> g
    float* rowAl = PT + (size_t)(768 + k)  * R + colb;  // al_raw
    float* rowG  = PT + (size_t)(1024 + k) * R + colb;  // g_raw
    float* rowBe = PT + (size_t)(1280 + k) * R + colb;  // be_raw
    float* rowPq = PT + (size_t)(1536 + k) * R + colb;  // phase query

    __shared__ float s_al[NSEQ + 256];
    __shared__ float s_rr[NSEQ + 256];
    __shared__ float s_ri[NSEQ + 256];
    __shared__ float s_sa[256], s_sbr[256], s_sbi[256];

    const float lam = *lambda_ptr;

    float cs_r[16], sn_r[16];          // fully unrolled -> stays in VGPRs

    #pragma unroll
    for (int i = 0; i < 16; i++) {
        int n = i * 256 + t;
        float araw = rowA[n];
        float wraw = rowW[n];
        float praw = rowP[n];
        float alraw = rowAl[n];
        float A     = 3.0f * sigm(araw);
        float alpha = sigm(alraw);
        float omega = softplusf_(wraw);
        float ang   = fmaf(omega, log1pf((float)n), praw);
        float sn, cs;
        sincosf(ang, &sn, &cs);
        cs_r[i] = cs;
        sn_r[i] = sn;
        float amp = (1.0f - alpha) * A;
        int pidx = n + (n >> 4);
        s_al[pidx] = alpha;
        s_rr[pidx] = amp * cs;
        s_ri[pidx] = amp * sn;
    }
    __syncthreads();

    {
        float ap = 1.0f, br = 0.0f, bi = 0.0f;
        int base = t * 17;
        #pragma unroll
        for (int i = 0; i < 16; i++) {
            float a = s_al[base + i];
            br = fmaf(a, br, s_rr[base + i]);
            bi = fmaf(a, bi, s_ri[base + i]);
            ap *= a;
        }
        s_sa[t] = ap; s_sbr[t] = br; s_sbi[t] = bi;
    }
    __syncthreads();

    for (int off = 1; off < 256; off <<= 1) {
        float a2 = s_sa[t], b2r = s_sbr[t], b2i = s_sbi[t];
        float a1 = 1.0f, b1r = 0.0f, b1i = 0.0f;
        if (t >= off) { a1 = s_sa[t - off]; b1r = s_sbr[t - off]; b1i = s_sbi[t - off]; }
        __syncthreads();
        s_sa[t]  = a1 * a2;
        s_sbr[t] = fmaf(a2, b1r, b2r);
        s_sbi[t] = fmaf(a2, b1i, b2i);
        __syncthreads();
    }

    {
        float cr = 0.0f, ci = 0.0f;
        if (t > 0) { cr = s_sbr[t - 1]; ci = s_sbi[t - 1]; }
        int base = t * 17;
        #pragma unroll
        for (int i = 0; i < 16; i++) {
            float a = s_al[base + i];
            cr = fmaf(a, cr, s_rr[base + i]);
            ci = fmaf(a, ci, s_ri[base + i]);
            s_rr[base + i] = cr;
            s_ri[base + i] = ci;
        }
    }
    __syncthreads();

    #pragma unroll
    for (int i = 0; i < 16; i++) {
        int n = i * 256 + t;
        float beraw = rowBe[n];
        float graw = rowG[n];
        float pq = rowPq[n];

        float cs = cs_r[i];
        float sn = sn_r[i];

        int pidx = n + (n >> 4);
        float rr = s_rr[pidx], ri = s_ri[pidx];
        float beta = sigm(beraw);
        float g = sigm(graw);

        float readout = rr * cs + ri * sn;
        rr -= beta * readout * cs;
        ri -= beta * readout * sn;

        float modulus = sqrtf(rr * rr + ri * ri + 1e-8f);
        float scale = fmaxf(modulus, 1.0f);
        rr /= scale; ri /= scale;

        float rho_re = rr * cs + ri * sn;
        float rho_im = -rr * sn + ri * cs;

        float rho_norm = sqrtf(rho_re * rho_re + rho_im * rho_im + 1e-8f);
        float sq, cq;
        sincosf(pq, &sq, &cq);
        float pa = (rho_re * cq + rho_im * sq) / rho_norm;
        float gate = sigm(lam * pa);
        rho_re *= gate;
        rho_im *= gate;

        rowA[n] = rho_re;
        rowW[n] = rho_im;
        rowP[n] = g;
    }
}

// ---------------------------------------------------------------------------
// pack_rho: fused cross-products + transpose + bf16 split.
// ---------------------------------------------------------------------------
__global__ __launch_bounds__(256) void pack_rho_kernel(
    const float* __restrict__ PT, unsigned short* __restrict__ RTH,
    unsigned short* __restrict__ RTL)
{
    __shared__ float s_re[256 * 33];
    __shared__ float s_im[256 * 33];
    __shared__ float s_g [256 * 33];

    const int tid = threadIdx.x;
    const int r0 = blockIdx.x * 32;

    {
        int lr = tid & 31;
        int k0 = tid >> 5;       // 0..7
        for (int it = 0; it < 32; it++) {
            int k = it * 8 + k0;
            size_t go = (size_t)k * NROW + r0 + lr;
            s_re[k * 33 + lr] = PT[go];
            s_im[k * 33 + lr] = PT[(size_t)256 * NROW + go];
            s_g [k * 33 + lr] = PT[(size_t)512 * NROW + go];
        }
    }
    __syncthreads();

    const int r = tid >> 3;      // 0..31
    const int c = tid & 7;       // 0..7
    for (int i = 0; i < 16; i++) {
        int jb = (c + 8 * i) * 8;       // 0..1016, step 8
        unsigned short h[8], l[8];
        #pragma unroll
        for (int e = 0; e < 8; e++) {
            int j = jb + e;
            float v;
            if (j < 256) {
                v = s_g[j * 33 + r] * s_re[j * 33 + r];
            } else if (j < 512) {
                int k = j - 256;
                v = s_g[k * 33 + r] * s_im[k * 33 + r];
            } else if (j < 767) {
                int k = j - 512;
                float gc = 0.5f * (s_g[k * 33 + r] + s_g[(k + 1) * 33 + r]);
                v = gc * (s_re[k * 33 + r] * s_re[(k + 1) * 33 + r]
                        - s_im[k * 33 + r] * s_im[(k + 1) * 33 + r]);
            } else if (j < 1022) {
                int k = j - 767;
                float gc = 0.5f * (s_g[k * 33 + r] + s_g[(k + 1) * 33 + r]);
                v = gc * (s_re[k * 33 + r] * s_im[(k + 1) * 33 + r]
                        + s_im[k * 33 + r] * s_re[(k + 1) * 33 + r]);
            } else {
                v = 0.0f;
            }
            bf16_split(v, h[e], l[e]);
        }
        size_t off = (size_t)(r0 + r) * 1024 + jb;
        s16x8 hv, lv;
        #pragma unroll
        for (int e = 0; e < 8; e++) { hv[e] = (short)h[e]; lv[e] = (short)l[e]; }
        *(s16x8*)&RTH[off] = hv;
        *(s16x8*)&RTL[off] = lv;
    }
}

// ---------------------------------------------------------------------------
// GEMM2 (2-term: W_res bf16, rho hi+lo): out[r,d] = rs * sum_j RT[r,j]*WP[d,j]
// Wave tile 128x64 (acc 8x4), block 256d x 128r. LDS bytes/MFMA: 6 -> 4 on
// reads; staging writes amortized over 2x output. Same 2-barrier skeleton,
// same K-order (absmax-preserving). Grid (128, 4) = 512 blocks, 2/CU.
// ---------------------------------------------------------------------------
__global__ __launch_bounds__(256, 2) void gemm2_kernel(
    const unsigned short* __restrict__ WPH,
    const unsigned short* __restrict__ RTH, const unsigned short* __restrict__ RTL,
    const float* __restrict__ rs_ptr, float* __restrict__ out)
{
    __shared__ __attribute__((aligned(16))) unsigned short AH[8192]; // 256x32
    __shared__ __attribute__((aligned(16))) unsigned short BH[4096]; // 128x32
    __shared__ __attribute__((aligned(16))) unsigned short BL[4096];

    const int tid  = threadIdx.x;
    const int lane = tid & 63;
    const int w    = tid >> 6;
    const int wm   = w >> 1;            // 0..1: d half (128)
    const int wn   = w & 1;             // 0..1: r half (64)
    const int m0   = blockIdx.y * 256;  // d tile
    const int n0   = blockIdx.x * 128;  // r tile
    const int fr   = lane & 15;
    const int fq   = lane >> 4;
    const float rs = *rs_ptr;

    f32x4 acc[8][4];
    #pragma unroll
    for (int i = 0; i < 8; i++)
        #pragma unroll
        for (int j = 0; j < 4; j++) acc[i][j] = (f32x4){0.f, 0.f, 0.f, 0.f};

    for (int kc = 0; kc < 32; kc++) {
        const int kbase = kc * 32;
        __syncthreads();
        // A: 1024 granules (256 rows x 4 ksubs)
        #pragma unroll
        for (int it = 0; it < 4; it++) {
            int G   = it * 256 + tid;
            int row = G & 255;
            int gq  = G >> 8;
            size_t offA = (size_t)(m0 + row) * 1024 + kbase + gq * 8;
            int ldsg = (it * 256 + w * 64) * 8;     // wave-uniform base
            GL2LDS(WPH + offA, &AH[ldsg]);
        }
        // B: 512 granules x 2 arrays
        #pragma unroll
        for (int it = 0; it < 2; it++) {
            int G   = it * 256 + tid;
            int row = G & 127;
            int gq  = G >> 7;
            size_t offB = (size_t)(n0 + row) * 1024 + kbase + gq * 8;
            int ldsg = (it * 256 + w * 64) * 8;
            GL2LDS(RTH + offB, &BH[ldsg]);
            GL2LDS(RTL + offB, &BL[ldsg]);
        }
        __syncthreads();

        s16x8 ah[8], bh[4], bl[4];
        #pragma unroll
        for (int i = 0; i < 8; i++)
            ah[i] = *(const s16x8*)&AH[(fq * 256 + wm * 128 + i * 16 + fr) * 8];
        #pragma unroll
        for (int j = 0; j < 4; j++) {
            int boff = (fq * 128 + wn * 64 + j * 16 + fr) * 8;
            bh[j] = *(const s16x8*)&BH[boff];
            bl[j] = *(const s16x8*)&BL[boff];
        }
        #pragma unroll
        for (int i = 0; i < 8; i++)
            #pragma unroll
            for (int j = 0; j < 4; j++) {
                acc[i][j] = __builtin_amdgcn_mfma_f32_16x16x32_bf16(ah[i], bh[j], acc[i][j], 0, 0, 0);
                acc[i][j] = __builtin_amdgcn_mfma_f32_16x16x32_bf16(ah[i], bl[j], acc[i][j], 0, 0, 0);
            }
    }

    #pragma unroll
    for (int i = 0; i < 8; i++) {
        int d = m0 + wm * 128 + i * 16 + fq * 4;
        #pragma unroll
        for (int j = 0; j < 4; j++) {
            int n = n0 + wn * 64 + j * 16 + fr;
            float4 v = { rs * acc[i][j][0], rs * acc[i][j][1],
                         rs * acc[i][j][2], rs * acc[i][j][3] };
            *(float4*)&out[(size_t)n * 1024 + d] = v;
        }
    }
}

// ---------------------------------------------------------------------------
extern "C" void kernel_launch(void* const* d_in, const int* in_sizes, int n_in,
                              void* d_out, int out_size, void* d_ws, size_t ws_size,
                              hipStream_t stream)
{
    const float* x      = (const float*)d_in[0];
    const float* Wproj  = (const float*)d_in[1];
    const float* bproj  = (const float*)d_in[2];
    const float* Wres   = (const float*)d_in[3];
    const float* Wphase = (const float*)d_in[4];
    const float* bphase = (const float*)d_in[5];
    const float* lam    = (const float*)d_in[6];
    const float* rs     = (const float*)d_in[7];
    float* out = (float*)d_out;

    // workspace layout (~124.8 MB):
    //   PT fp32 [1792][16384]           (117.4 MB)
    //   WH, WL bf16 [1792][1024]        (7.3 MB, after PT)
    // aliased into dead PT rows:
    //   RTH bf16 [16384][1024] = PT rows  768..1279
    //   RTL bf16 [16384][1024] = PT rows 1280..1791
    //   WPH bf16 [1024][1024]  = PT rows 0..31 (after pack_rho)
    // d_out doubles as XH/XL bf16 scratch until gemm2 overwrites it.
    float* PT = (float*)d_ws;
    unsigned short* WH  = (unsigned short*)((char*)d_ws + (size_t)JTOT * NROW * 4);
    unsigned short* WL  = WH + (size_t)JTOT * 1024;
    unsigned short* RTH = (unsigned short*)(PT + (size_t)768 * NROW);
    unsigned short* RTL = RTH + (size_t)NROW * 1024;
    unsigned short* WPH = (unsigned short*)PT;
    unsigned short* XH  = (unsigned short*)d_out;
    unsigned short* XL  = XH + (size_t)NROW * 1024;

    hipLaunchKernelGGL(split_x_kernel, dim3(NROW * D_MODEL / 1024), dim3(256), 0, stream,
                       x, XH, XL);
    hipLaunchKernelGGL(split_w_kernel, dim3(JTOT * D_MODEL / 1024), dim3(256), 0, stream,
                       Wproj, Wphase, WH, WL);
    hipLaunchKernelGGL(gemm1_full_kernel, dim3(NROW / 128, 4), dim3(256), 0, stream,
                       WH, WL, XH, XL, bproj, PT);
    hipLaunchKernelGGL(gemm1_lite_kernel, dim3(NROW / 128, 5), dim3(256), 0, stream,
                       WH, XH, bproj, bphase, PT);
    hipLaunchKernelGGL(scan_kernel, dim3(BATCH * KOSC), dim3(256), 0, stream,
                       PT, lam);
    hipLaunchKernelGGL(pack_rho_kernel, dim3(NROW / 32), dim3(256), 0, stream,
                       PT, RTH, RTL);
    hipLaunchKernelGGL(pack_wres_kernel, dim3(1024 * 1024 / 256), dim3(256), 0, stream,
                       Wres, WPH);
    hipLaunchKernelGGL(gemm2_kernel, dim3(NROW / 128, 1024 / 256), dim3(256), 0, stream,
                       WPH, RTH, RTL, rs, out);
}

// Round 9
// 515.293 us; speedup vs baseline: 1.3711x; 1.0214x over previous
//
#include <hip/hip_runtime.h>
#include <cmath>

// Problem constants
#define D_MODEL 1024
#define KOSC    256
#define NSEQ    4096
#define BATCH   4
#define NROW    (BATCH * NSEQ)   // 16384 rows (b*n)
#define JTOT    1792             // 6K proj + K phase

typedef short      s16x8 __attribute__((ext_vector_type(8)));
typedef float      f32x4 __attribute__((ext_vector_type(4)));

// async global->LDS, 16B per lane; LDS dest = wave-uniform base + lane*16
#define GL2LDS(gsrc, ldst)                                                      \
  __builtin_amdgcn_global_load_lds(                                             \
      (const __attribute__((address_space(1))) unsigned int*)(gsrc),            \
      (__attribute__((address_space(3))) unsigned int*)(ldst), 16, 0, 0)

__device__ __forceinline__ float sigm(float x) {
    return 1.0f / (1.0f + expf(-x));
}
__device__ __forceinline__ float softplusf_(float x) {
    return fmaxf(x, 0.0f) + log1pf(expf(-fabsf(x)));
}

// round-to-nearest-even bf16 split: f = hi + lo, residual ~2^-18 * |f|
__device__ __forceinline__ void bf16_split(float f, unsigned short& hi,
                                           unsigned short& lo) {
    unsigned u = __float_as_uint(f);
    unsigned r = u + 0x7FFFu + ((u >> 16) & 1u);
    hi = (unsigned short)(r >> 16);
    float fh = __uint_as_float((unsigned)hi << 16);
    float fl = f - fh;
    unsigned ul = __float_as_uint(fl);
    unsigned rl = ul + 0x7FFFu + ((ul >> 16) & 1u);
    lo = (unsigned short)(rl >> 16);
}

// ---------------------------------------------------------------------------
// split_x: x fp32 (16384x1024) -> XH, XL bf16 (in d_out scratch)
// ---------------------------------------------------------------------------
__global__ __launch_bounds__(256) void split_x_kernel(
    const float* __restrict__ x, unsigned short* __restrict__ XH,
    unsigned short* __restrict__ XL)
{
    int i = blockIdx.x * 256 + threadIdx.x;    // x4 floats
    float4 v = ((const float4*)x)[i];
    ushort4 h, l;
    bf16_split(v.x, h.x, l.x);
    bf16_split(v.y, h.y, l.y);
    bf16_split(v.z, h.z, l.z);
    bf16_split(v.w, h.w, l.w);
    ((ushort4*)XH)[i] = h;
    ((ushort4*)XL)[i] = l;
}

// ---------------------------------------------------------------------------
// split_w: [Wproj;Wphase] fp32 (1792x1024) -> WH, WL bf16
// ---------------------------------------------------------------------------
__global__ __launch_bounds__(256) void split_w_kernel(
    const float* __restrict__ Wproj, const float* __restrict__ Wphase,
    unsigned short* __restrict__ WH, unsigned short* __restrict__ WL)
{
    int i = blockIdx.x * 256 + threadIdx.x;    // x4 floats
    int elem = i << 2;
    int row = elem >> 10;
    int col = elem & 1023;
    const float* src = (row < 1536) ? (Wproj + (size_t)row * 1024 + col)
                                    : (Wphase + (size_t)(row - 1536) * 1024 + col);
    float4 v = *(const float4*)src;
    ushort4 h, l;
    bf16_split(v.x, h.x, l.x);
    bf16_split(v.y, h.y, l.y);
    bf16_split(v.z, h.z, l.z);
    bf16_split(v.w, h.w, l.w);
    ((ushort4*)WH)[i] = h;
    ((ushort4*)WL)[i] = l;
}

// ---------------------------------------------------------------------------
// pack_wres: W_res fp32 (1024 x 1022) -> WPH bf16 (1024 x 1024), padded 0
// ---------------------------------------------------------------------------
__global__ __launch_bounds__(256) void pack_wres_kernel(
    const float* __restrict__ Wres, unsigned short* __restrict__ WPH)
{
    int idx = blockIdx.x * 256 + threadIdx.x;   // 0 .. 1024*1024-1
    int d = idx >> 10;
    int j = idx & 1023;
    float v = (j < 1022) ? Wres[(size_t)d * 1022 + j] : 0.0f;
    unsigned u = __float_as_uint(v);
    unsigned r = u + 0x7FFFu + ((u >> 16) & 1u);
    WPH[idx] = (unsigned short)(r >> 16);
}

// ---------------------------------------------------------------------------
// GEMM1-full (3-term split-bf16): PT rows 256..767 (omega, phi) — these feed
// the oscillator angle (amplified by log-position <= 8.3) and need ~fp32.
//   jt = blockIdx.y + 2
// (round-2 proven structure)
// ---------------------------------------------------------------------------
__global__ __launch_bounds__(256, 3) void gemm1_full_kernel(
    const unsigned short* __restrict__ WH, const unsigned short* __restrict__ WL,
    const unsigned short* __restrict__ XH, const unsigned short* __restrict__ XL,
    const float* __restrict__ bproj, float* __restrict__ PT)
{
    __shared__ __attribute__((aligned(16))) unsigned short AH[4096];
    __shared__ __attribute__((aligned(16))) unsigned short AL[4096];
    __shared__ __attribute__((aligned(16))) unsigned short BH[4096];
    __shared__ __attribute__((aligned(16))) unsigned short BL[4096];

    const int tid  = threadIdx.x;
    const int lane = tid & 63;
    const int w    = tid >> 6;          // wave 0..3
    const int wm   = w >> 1, wn = w & 1;
    const int m0   = (blockIdx.y + 2) * 128;  // j tile (rows 256..767)
    const int n0   = blockIdx.x * 128;        // r tile
    const int fr   = lane & 15;
    const int fq   = lane >> 4;         // 0..3

    f32x4 acc[4][4];
    #pragma unroll
    for (int i = 0; i < 4; i++)
        #pragma unroll
        for (int j = 0; j < 4; j++) acc[i][j] = (f32x4){0.f, 0.f, 0.f, 0.f};

    for (int kc = 0; kc < 32; kc++) {
        const int kbase = kc * 32;
        __syncthreads();
        #pragma unroll
        for (int t = 0; t < 2; t++) {
            int G  = w * 128 + t * 64 + lane;       // granule index 0..511
            int gm = G & 127;
            int gq = G >> 7;
            size_t offA = (size_t)(m0 + gm) * 1024 + kbase + gq * 8;
            size_t offB = (size_t)(n0 + gm) * 1024 + kbase + gq * 8;
            int ldsg = (w * 128 + t * 64) * 8;      // wave-uniform base (shorts)
            GL2LDS(WH + offA, &AH[ldsg]);
            GL2LDS(WL + offA, &AL[ldsg]);
            GL2LDS(XH + offB, &BH[ldsg]);
            GL2LDS(XL + offB, &BL[ldsg]);
        }
        __syncthreads();

        s16x8 ah[4], al[4], bh[4], bl[4];
        #pragma unroll
        for (int f = 0; f < 4; f++) {
            int aoff = (fq * 128 + wm * 64 + f * 16 + fr) * 8;
            int boff = (fq * 128 + wn * 64 + f * 16 + fr) * 8;
            ah[f] = *(const s16x8*)&AH[aoff];
            al[f] = *(const s16x8*)&AL[aoff];
            bh[f] = *(const s16x8*)&BH[boff];
            bl[f] = *(const s16x8*)&BL[boff];
        }
        #pragma unroll
        for (int i = 0; i < 4; i++)
            #pragma unroll
            for (int j = 0; j < 4; j++) {
                acc[i][j] = __builtin_amdgcn_mfma_f32_16x16x32_bf16(ah[i], bh[j], acc[i][j], 0, 0, 0);
                acc[i][j] = __builtin_amdgcn_mfma_f32_16x16x32_bf16(ah[i], bl[j], acc[i][j], 0, 0, 0);
                acc[i][j] = __builtin_amdgcn_mfma_f32_16x16x32_bf16(al[i], bh[j], acc[i][j], 0, 0, 0);
            }
    }

    #pragma unroll
    for (int i = 0; i < 4; i++) {
        int mbase = m0 + wm * 64 + i * 16 + fq * 4;
        #pragma unroll
        for (int j = 0; j < 4; j++) {
            int n = n0 + wn * 64 + j * 16 + fr;
            #pragma unroll
            for (int rg = 0; rg < 4; rg++) {
                int m = mbase + rg;
                PT[(size_t)m * NROW + n] = acc[i][j][rg] + bproj[m];
            }
        }
    }
}

// ---------------------------------------------------------------------------
// GEMM1-lite (single bf16): PT rows 0..255, 768..1791. BK=64, 128x128 tiles,
// grid (128,10) = 1280 blocks = 5/CU, 4 resident — zero-tail, proven in r2.
// (r8's 256x128 tile regressed on grid geometry: 640 blocks = 2.5/CU tail.)
//   jt = (blockIdx.y < 2) ? blockIdx.y : blockIdx.y + 4
// ---------------------------------------------------------------------------
__global__ __launch_bounds__(256, 4) void gemm1_lite_kernel(
    const unsigned short* __restrict__ WH, const unsigned short* __restrict__ XH,
    const float* __restrict__ bproj, const float* __restrict__ bphase,
    float* __restrict__ PT)
{
    __shared__ __attribute__((aligned(16))) unsigned short AH[8192]; // 128x64
    __shared__ __attribute__((aligned(16))) unsigned short BH[8192];

    const int tid  = threadIdx.x;
    const int lane = tid & 63;
    const int w    = tid >> 6;
    const int wm   = w >> 1, wn = w & 1;
    const int yt   = blockIdx.y;
    const int jt   = (yt < 2) ? yt : yt + 4;
    const int m0   = jt * 128;
    const int n0   = blockIdx.x * 128;
    const int fr   = lane & 15;
    const int fq   = lane >> 4;

    f32x4 acc[4][4];
    #pragma unroll
    for (int i = 0; i < 4; i++)
        #pragma unroll
        for (int j = 0; j < 4; j++) acc[i][j] = (f32x4){0.f, 0.f, 0.f, 0.f};

    for (int kc = 0; kc < 16; kc++) {
        const int kbase = kc * 64;
        __syncthreads();
        #pragma unroll
        for (int t = 0; t < 4; t++) {
            int G  = t * 256 + tid;                 // granule index 0..1023
            int gm = G & 127;
            int gq = G >> 7;                        // ksub 0..7
            size_t offA = (size_t)(m0 + gm) * 1024 + kbase + gq * 8;
            size_t offB = (size_t)(n0 + gm) * 1024 + kbase + gq * 8;
            int ldsg = (t * 256 + w * 64) * 8;      // wave-uniform base (shorts)
            GL2LDS(WH + offA, &AH[ldsg]);
            GL2LDS(XH + offB, &BH[ldsg]);
        }
        __syncthreads();

        #pragma unroll
        for (int s = 0; s < 2; s++) {
            s16x8 ah[4], bh[4];
            #pragma unroll
            for (int f = 0; f < 4; f++) {
                int aoff = (((s * 4 + fq) * 128) + wm * 64 + f * 16 + fr) * 8;
                int boff = (((s * 4 + fq) * 128) + wn * 64 + f * 16 + fr) * 8;
                ah[f] = *(const s16x8*)&AH[aoff];
                bh[f] = *(const s16x8*)&BH[boff];
            }
            #pragma unroll
            for (int i = 0; i < 4; i++)
                #pragma unroll
                for (int j = 0; j < 4; j++)
                    acc[i][j] = __builtin_amdgcn_mfma_f32_16x16x32_bf16(ah[i], bh[j], acc[i][j], 0, 0, 0);
        }
    }

    #pragma unroll
    for (int i = 0; i < 4; i++) {
        int mbase = m0 + wm * 64 + i * 16 + fq * 4;
        #pragma unroll
        for (int j = 0; j < 4; j++) {
            int n = n0 + wn * 64 + j * 16 + fr;
            #pragma unroll
            for (int rg = 0; rg < 4; rg++) {
                int m = mbase + rg;
                float bias = (m < 1536) ? bproj[m] : bphase[m - 1536];
                PT[(size_t)m * NROW + n] = acc[i][j][rg] + bias;
            }
        }
    }
}

// ---------------------------------------------------------------------------
// Scan kernel (round-2 proven): one block per (b, k) channel. cs/sn carried
// in registers between pass 1 and pass 3.
// ---------------------------------------------------------------------------
__global__ __launch_bounds__(256) void scan_kernel(float* PT,
                                                   const float* lambda_ptr)
{
    const int bx = blockIdx.x;         // 0..1023
    const int k = bx & 255;
    const int b = bx >> 8;
    const int t = threadIdx.x;         // 0..255
    const size_t colb = (size_t)b * NSEQ;
    const size_t R = NROW;

    float* rowA  = PT + (size_t)(k)        * R + colb;  // a_raw -> rho_re
    float* rowW  = PT + (size_t)(256 + k)  * R + colb;  // w_raw -> rho_im
    float* rowP  = PT + (size_t)(512 + k)  * R + colb;  // p_raw -> g
    float* rowAl = PT + (size_t)(768 + k)  * R + colb;  // al_raw
    float* rowG  = PT + (size_t)(1024 + k) * R + colb;  // g_raw
    float* rowBe = PT + (size_t)(1280 + k) * R + colb;  // be_raw
    float* rowPq = PT + (size_t)(1536 + k) * R + colb;  // phase query

    __shared__ float s_al[NSEQ + 256];
    __shared__ float s_rr[NSEQ + 256];
    __shared__ float s_ri[NSEQ + 256];
    __shared__ float s_sa[256], s_sbr[256], s_sbi[256];

    const float lam = *lambda_ptr;

    float cs_r[16], sn_r[16];          // fully unrolled -> stays in VGPRs

    #pragma unroll
    for (int i = 0; i < 16; i++) {
        int n = i * 256 + t;
        float araw = rowA[n];
        float wraw = rowW[n];
        float praw = rowP[n];
        float alraw = rowAl[n];
        float A     = 3.0f * sigm(araw);
        float alpha = sigm(alraw);
        float omega = softplusf_(wraw);
        float ang   = fmaf(omega, log1pf((float)n), praw);
        float sn, cs;
        sincosf(ang, &sn, &cs);
        cs_r[i] = cs;
        sn_r[i] = sn;
        float amp = (1.0f - alpha) * A;
        int pidx = n + (n >> 4);
        s_al[pidx] = alpha;
        s_rr[pidx] = amp * cs;
        s_ri[pidx] = amp * sn;
    }
    __syncthreads();

    {
        float ap = 1.0f, br = 0.0f, bi = 0.0f;
        int base = t * 17;
        #pragma unroll
        for (int i = 0; i < 16; i++) {
            float a = s_al[base + i];
            br = fmaf(a, br, s_rr[base + i]);
            bi = fmaf(a, bi, s_ri[base + i]);
            ap *= a;
        }
        s_sa[t] = ap; s_sbr[t] = br; s_sbi[t] = bi;
    }
    __syncthreads();

    for (int off = 1; off < 256; off <<= 1) {
        float a2 = s_sa[t], b2r = s_sbr[t], b2i = s_sbi[t];
        float a1 = 1.0f, b1r = 0.0f, b1i = 0.0f;
        if (t >= off) { a1 = s_sa[t - off]; b1r = s_sbr[t - off]; b1i = s_sbi[t - off]; }
        __syncthreads();
        s_sa[t]  = a1 * a2;
        s_sbr[t] = fmaf(a2, b1r, b2r);
        s_sbi[t] = fmaf(a2, b1i, b2i);
        __syncthreads();
    }

    {
        float cr = 0.0f, ci = 0.0f;
        if (t > 0) { cr = s_sbr[t - 1]; ci = s_sbi[t - 1]; }
        int base = t * 17;
        #pragma unroll
        for (int i = 0; i < 16; i++) {
            float a = s_al[base + i];
            cr = fmaf(a, cr, s_rr[base + i]);
            ci = fmaf(a, ci, s_ri[base + i]);
            s_rr[base + i] = cr;
            s_ri[base + i] = ci;
        }
    }
    __syncthreads();

    #pragma unroll
    for (int i = 0; i < 16; i++) {
        int n = i * 256 + t;
        float beraw = rowBe[n];
        float graw = rowG[n];
        float pq = rowPq[n];

        float cs = cs_r[i];
        float sn = sn_r[i];

        int pidx = n + (n >> 4);
        float rr = s_rr[pidx], ri = s_ri[pidx];
        float beta = sigm(beraw);
        float g = sigm(graw);

        float readout = rr * cs + ri * sn;
        rr -= beta * readout * cs;
        ri -= beta * readout * sn;

        float modulus = sqrtf(rr * rr + ri * ri + 1e-8f);
        float scale = fmaxf(modulus, 1.0f);
        rr /= scale; ri /= scale;

        float rho_re = rr * cs + ri * sn;
        float rho_im = -rr * sn + ri * cs;

        float rho_norm = sqrtf(rho_re * rho_re + rho_im * rho_im + 1e-8f);
        float sq, cq;
        sincosf(pq, &sq, &cq);
        float pa = (rho_re * cq + rho_im * sq) / rho_norm;
        float gate = sigm(lam * pa);
        rho_re *= gate;
        rho_im *= gate;

        rowA[n] = rho_re;
        rowW[n] = rho_im;
        rowP[n] = g;
    }
}

// ---------------------------------------------------------------------------
// pack_rho: fused cross-products + transpose + bf16 split.
// ---------------------------------------------------------------------------
__global__ __launch_bounds__(256) void pack_rho_kernel(
    const float* __restrict__ PT, unsigned short* __restrict__ RTH,
    unsigned short* __restrict__ RTL)
{
    __shared__ float s_re[256 * 33];
    __shared__ float s_im[256 * 33];
    __shared__ float s_g [256 * 33];

    const int tid = threadIdx.x;
    const int r0 = blockIdx.x * 32;

    {
        int lr = tid & 31;
        int k0 = tid >> 5;       // 0..7
        for (int it = 0; it < 32; it++) {
            int k = it * 8 + k0;
            size_t go = (size_t)k * NROW + r0 + lr;
            s_re[k * 33 + lr] = PT[go];
            s_im[k * 33 + lr] = PT[(size_t)256 * NROW + go];
            s_g [k * 33 + lr] = PT[(size_t)512 * NROW + go];
        }
    }
    __syncthreads();

    const int r = tid >> 3;      // 0..31
    const int c = tid & 7;       // 0..7
    for (int i = 0; i < 16; i++) {
        int jb = (c + 8 * i) * 8;       // 0..1016, step 8
        unsigned short h[8], l[8];
        #pragma unroll
        for (int e = 0; e < 8; e++) {
            int j = jb + e;
            float v;
            if (j < 256) {
                v = s_g[j * 33 + r] * s_re[j * 33 + r];
            } else if (j < 512) {
                int k = j - 256;
                v = s_g[k * 33 + r] * s_im[k * 33 + r];
            } else if (j < 767) {
                int k = j - 512;
                float gc = 0.5f * (s_g[k * 33 + r] + s_g[(k + 1) * 33 + r]);
                v = gc * (s_re[k * 33 + r] * s_re[(k + 1) * 33 + r]
                        - s_im[k * 33 + r] * s_im[(k + 1) * 33 + r]);
            } else if (j < 1022) {
                int k = j - 767;
                float gc = 0.5f * (s_g[k * 33 + r] + s_g[(k + 1) * 33 + r]);
                v = gc * (s_re[k * 33 + r] * s_im[(k + 1) * 33 + r]
                        + s_im[k * 33 + r] * s_re[(k + 1) * 33 + r]);
            } else {
                v = 0.0f;
            }
            bf16_split(v, h[e], l[e]);
        }
        size_t off = (size_t)(r0 + r) * 1024 + jb;
        s16x8 hv, lv;
        #pragma unroll
        for (int e = 0; e < 8; e++) { hv[e] = (short)h[e]; lv[e] = (short)l[e]; }
        *(s16x8*)&RTH[off] = hv;
        *(s16x8*)&RTL[off] = lv;
    }
}

// ---------------------------------------------------------------------------
// GEMM2 (2-term: W_res bf16, rho hi+lo): out[r,d] = rs * sum_j RT[r,j]*WP[d,j]
// Wave tile 128x64 (acc 8x4), block 256d x 128r (round-8 proven: dropped out
// of top-5). Grid (128, 4) = 512 blocks = exactly 2/CU, zero tail.
// ---------------------------------------------------------------------------
__global__ __launch_bounds__(256, 2) void gemm2_kernel(
    const unsigned short* __restrict__ WPH,
    const unsigned short* __restrict__ RTH, const unsigned short* __restrict__ RTL,
    const float* __restrict__ rs_ptr, float* __restrict__ out)
{
    __shared__ __attribute__((aligned(16))) unsigned short AH[8192]; // 256x32
    __shared__ __attribute__((aligned(16))) unsigned short BH[4096]; // 128x32
    __shared__ __attribute__((aligned(16))) unsigned short BL[4096];

    const int tid  = threadIdx.x;
    const int lane = tid & 63;
    const int w    = tid >> 6;
    const int wm   = w >> 1;            // 0..1: d half (128)
    const int wn   = w & 1;             // 0..1: r half (64)
    const int m0   = blockIdx.y * 256;  // d tile
    const int n0   = blockIdx.x * 128;  // r tile
    const int fr   = lane & 15;
    const int fq   = lane >> 4;
    const float rs = *rs_ptr;

    f32x4 acc[8][4];
    #pragma unroll
    for (int i = 0; i < 8; i++)
        #pragma unroll
        for (int j = 0; j < 4; j++) acc[i][j] = (f32x4){0.f, 0.f, 0.f, 0.f};

    for (int kc = 0; kc < 32; kc++) {
        const int kbase = kc * 32;
        __syncthreads();
        // A: 1024 granules (256 rows x 4 ksubs)
        #pragma unroll
        for (int it = 0; it < 4; it++) {
            int G   = it * 256 + tid;
            int row = G & 255;
            int gq  = G >> 8;
            size_t offA = (size_t)(m0 + row) * 1024 + kbase + gq * 8;
            int ldsg = (it * 256 + w * 64) * 8;     // wave-uniform base
            GL2LDS(WPH + offA, &AH[ldsg]);
        }
        // B: 512 granules x 2 arrays
        #pragma unroll
        for (int it = 0; it < 2; it++) {
            int G   = it * 256 + tid;
            int row = G & 127;
            int gq  = G >> 7;
            size_t offB = (size_t)(n0 + row) * 1024 + kbase + gq * 8;
            int ldsg = (it * 256 + w * 64) * 8;
            GL2LDS(RTH + offB, &BH[ldsg]);
            GL2LDS(RTL + offB, &BL[ldsg]);
        }
        __syncthreads();

        s16x8 ah[8], bh[4], bl[4];
        #pragma unroll
        for (int i = 0; i < 8; i++)
            ah[i] = *(const s16x8*)&AH[(fq * 256 + wm * 128 + i * 16 + fr) * 8];
        #pragma unroll
        for (int j = 0; j < 4; j++) {
            int boff = (fq * 128 + wn * 64 + j * 16 + fr) * 8;
            bh[j] = *(const s16x8*)&BH[boff];
            bl[j] = *(const s16x8*)&BL[boff];
        }
        #pragma unroll
        for (int i = 0; i < 8; i++)
            #pragma unroll
            for (int j = 0; j < 4; j++) {
                acc[i][j] = __builtin_amdgcn_mfma_f32_16x16x32_bf16(ah[i], bh[j], acc[i][j], 0, 0, 0);
                acc[i][j] = __builtin_amdgcn_mfma_f32_16x16x32_bf16(ah[i], bl[j], acc[i][j], 0, 0, 0);
            }
    }

    #pragma unroll
    for (int i = 0; i < 8; i++) {
        int d = m0 + wm * 128 + i * 16 + fq * 4;
        #pragma unroll
        for (int j = 0; j < 4; j++) {
            int n = n0 + wn * 64 + j * 16 + fr;
            float4 v = { rs * acc[i][j][0], rs * acc[i][j][1],
                         rs * acc[i][j][2], rs * acc[i][j][3] };
            *(float4*)&out[(size_t)n * 1024 + d] = v;
        }
    }
}

// ---------------------------------------------------------------------------
extern "C" void kernel_launch(void* const* d_in, const int* in_sizes, int n_in,
                              void* d_out, int out_size, void* d_ws, size_t ws_size,
                              hipStream_t stream)
{
    const float* x      = (const float*)d_in[0];
    const float* Wproj  = (const float*)d_in[1];
    const float* bproj  = (const float*)d_in[2];
    const float* Wres   = (const float*)d_in[3];
    const float* Wphase = (const float*)d_in[4];
    const float* bphase = (const float*)d_in[5];
    const float* lam    = (const float*)d_in[6];
    const float* rs     = (const float*)d_in[7];
    float* out = (float*)d_out;

    // workspace layout (~124.8 MB):
    //   PT fp32 [1792][16384]           (117.4 MB)
    //   WH, WL bf16 [1792][1024]        (7.3 MB, after PT)
    // aliased into dead PT rows:
    //   RTH bf16 [16384][1024] = PT rows  768..1279
    //   RTL bf16 [16384][1024] = PT rows 1280..1791
    //   WPH bf16 [1024][1024]  = PT rows 0..31 (after pack_rho)
    // d_out doubles as XH/XL bf16 scratch until gemm2 overwrites it.
    float* PT = (float*)d_ws;
    unsigned short* WH  = (unsigned short*)((char*)d_ws + (size_t)JTOT * NROW * 4);
    unsigned short* WL  = WH + (size_t)JTOT * 1024;
    unsigned short* RTH = (unsigned short*)(PT + (size_t)768 * NROW);
    unsigned short* RTL = RTH + (size_t)NROW * 1024;
    unsigned short* WPH = (unsigned short*)PT;
    unsigned short* XH  = (unsigned short*)d_out;
    unsigned short* XL  = XH + (size_t)NROW * 1024;

    hipLaunchKernelGGL(split_x_kernel, dim3(NROW * D_MODEL / 1024), dim3(256), 0, stream,
                       x, XH, XL);
    hipLaunchKernelGGL(split_w_kernel, dim3(JTOT * D_MODEL / 1024), dim3(256), 0, stream,
                       Wproj, Wphase, WH, WL);
    hipLaunchKernelGGL(gemm1_full_kernel, dim3(NROW / 128, 4), dim3(256), 0, stream,
                       WH, WL, XH, XL, bproj, PT);
    hipLaunchKernelGGL(gemm1_lite_kernel, dim3(NROW / 128, 10), dim3(256), 0, stream,
                       WH, XH, bproj, bphase, PT);
    hipLaunchKernelGGL(scan_kernel, dim3(BATCH * KOSC), dim3(256), 0, stream,
                       PT, lam);
    hipLaunchKernelGGL(pack_rho_kernel, dim3(NROW / 32), dim3(256), 0, stream,
                       PT, RTH, RTL);
    hipLaunchKernelGGL(pack_wres_kernel, dim3(1024 * 1024 / 256), dim3(256), 0, stream,
                       Wres, WPH);
    hipLaunchKernelGGL(gemm2_kernel, dim3(NROW / 128, 1024 / 256), dim3(256), 0, stream,
                       WPH, RTH, RTL, rs, out);
}

// Round 10
// 504.973 us; speedup vs baseline: 1.3991x; 1.0204x over previous
//
#include <hip/hip_runtime.h>
#include <cmath>

// Problem constants
#define D_MODEL 1024
#define KOSC    256
#define NSEQ    4096
#define BATCH   4
#define NROW    (BATCH * NSEQ)   // 16384 rows (b*n)
#define JTOT    1792             // 6K proj + K phase

typedef short      s16x8 __attribute__((ext_vector_type(8)));
typedef float      f32x4 __attribute__((ext_vector_type(4)));

// async global->LDS, 16B per lane; LDS dest = wave-uniform base + lane*16
#define GL2LDS(gsrc, ldst)                                                      \
  __builtin_amdgcn_global_load_lds(                                             \
      (const __attribute__((address_space(1))) unsigned int*)(gsrc),            \
      (__attribute__((address_space(3))) unsigned int*)(ldst), 16, 0, 0)

__device__ __forceinline__ float sigm(float x) {
    return 1.0f / (1.0f + expf(-x));
}
__device__ __forceinline__ float softplusf_(float x) {
    return fmaxf(x, 0.0f) + log1pf(expf(-fabsf(x)));
}

// round-to-nearest-even bf16 split: f = hi + lo, residual ~2^-18 * |f|
__device__ __forceinline__ void bf16_split(float f, unsigned short& hi,
                                           unsigned short& lo) {
    unsigned u = __float_as_uint(f);
    unsigned r = u + 0x7FFFu + ((u >> 16) & 1u);
    hi = (unsigned short)(r >> 16);
    float fh = __uint_as_float((unsigned)hi << 16);
    float fl = f - fh;
    unsigned ul = __float_as_uint(fl);
    unsigned rl = ul + 0x7FFFu + ((ul >> 16) & 1u);
    lo = (unsigned short)(rl >> 16);
}

// ---------------------------------------------------------------------------
// split_x: x fp32 (16384x1024) -> XH, XL bf16 (in d_out scratch)
// ---------------------------------------------------------------------------
__global__ __launch_bounds__(256) void split_x_kernel(
    const float* __restrict__ x, unsigned short* __restrict__ XH,
    unsigned short* __restrict__ XL)
{
    int i = blockIdx.x * 256 + threadIdx.x;    // x4 floats
    float4 v = ((const float4*)x)[i];
    ushort4 h, l;
    bf16_split(v.x, h.x, l.x);
    bf16_split(v.y, h.y, l.y);
    bf16_split(v.z, h.z, l.z);
    bf16_split(v.w, h.w, l.w);
    ((ushort4*)XH)[i] = h;
    ((ushort4*)XL)[i] = l;
}

// ---------------------------------------------------------------------------
// split_w: [Wproj;Wphase] fp32 (1792x1024) -> WH, WL bf16
// ---------------------------------------------------------------------------
__global__ __launch_bounds__(256) void split_w_kernel(
    const float* __restrict__ Wproj, const float* __restrict__ Wphase,
    unsigned short* __restrict__ WH, unsigned short* __restrict__ WL)
{
    int i = blockIdx.x * 256 + threadIdx.x;    // x4 floats
    int elem = i << 2;
    int row = elem >> 10;
    int col = elem & 1023;
    const float* src = (row < 1536) ? (Wproj + (size_t)row * 1024 + col)
                                    : (Wphase + (size_t)(row - 1536) * 1024 + col);
    float4 v = *(const float4*)src;
    ushort4 h, l;
    bf16_split(v.x, h.x, l.x);
    bf16_split(v.y, h.y, l.y);
    bf16_split(v.z, h.z, l.z);
    bf16_split(v.w, h.w, l.w);
    ((ushort4*)WH)[i] = h;
    ((ushort4*)WL)[i] = l;
}

// ---------------------------------------------------------------------------
// pack_wres: W_res fp32 (1024 x 1022) -> WPH bf16 (1024 x 1024), padded 0
// ---------------------------------------------------------------------------
__global__ __launch_bounds__(256) void pack_wres_kernel(
    const float* __restrict__ Wres, unsigned short* __restrict__ WPH)
{
    int idx = blockIdx.x * 256 + threadIdx.x;   // 0 .. 1024*1024-1
    int d = idx >> 10;
    int j = idx & 1023;
    float v = (j < 1022) ? Wres[(size_t)d * 1022 + j] : 0.0f;
    unsigned u = __float_as_uint(v);
    unsigned r = u + 0x7FFFu + ((u >> 16) & 1u);
    WPH[idx] = (unsigned short)(r >> 16);
}

// ---------------------------------------------------------------------------
// GEMM1-full (3-term split-bf16): PT rows 256..767 (omega, phi) — these feed
// the oscillator angle (amplified by log-position <= 8.3) and need ~fp32.
//   jt = blockIdx.y + 2
// (round-2 proven structure)
// ---------------------------------------------------------------------------
__global__ __launch_bounds__(256, 3) void gemm1_full_kernel(
    const unsigned short* __restrict__ WH, const unsigned short* __restrict__ WL,
    const unsigned short* __restrict__ XH, const unsigned short* __restrict__ XL,
    const float* __restrict__ bproj, float* __restrict__ PT)
{
    __shared__ __attribute__((aligned(16))) unsigned short AH[4096];
    __shared__ __attribute__((aligned(16))) unsigned short AL[4096];
    __shared__ __attribute__((aligned(16))) unsigned short BH[4096];
    __shared__ __attribute__((aligned(16))) unsigned short BL[4096];

    const int tid  = threadIdx.x;
    const int lane = tid & 63;
    const int w    = tid >> 6;          // wave 0..3
    const int wm   = w >> 1, wn = w & 1;
    const int m0   = (blockIdx.y + 2) * 128;  // j tile (rows 256..767)
    const int n0   = blockIdx.x * 128;        // r tile
    const int fr   = lane & 15;
    const int fq   = lane >> 4;         // 0..3

    f32x4 acc[4][4];
    #pragma unroll
    for (int i = 0; i < 4; i++)
        #pragma unroll
        for (int j = 0; j < 4; j++) acc[i][j] = (f32x4){0.f, 0.f, 0.f, 0.f};

    for (int kc = 0; kc < 32; kc++) {
        const int kbase = kc * 32;
        __syncthreads();
        #pragma unroll
        for (int t = 0; t < 2; t++) {
            int G  = w * 128 + t * 64 + lane;       // granule index 0..511
            int gm = G & 127;
            int gq = G >> 7;
            size_t offA = (size_t)(m0 + gm) * 1024 + kbase + gq * 8;
            size_t offB = (size_t)(n0 + gm) * 1024 + kbase + gq * 8;
            int ldsg = (w * 128 + t * 64) * 8;      // wave-uniform base (shorts)
            GL2LDS(WH + offA, &AH[ldsg]);
            GL2LDS(WL + offA, &AL[ldsg]);
            GL2LDS(XH + offB, &BH[ldsg]);
            GL2LDS(XL + offB, &BL[ldsg]);
        }
        __syncthreads();

        s16x8 ah[4], al[4], bh[4], bl[4];
        #pragma unroll
        for (int f = 0; f < 4; f++) {
            int aoff = (fq * 128 + wm * 64 + f * 16 + fr) * 8;
            int boff = (fq * 128 + wn * 64 + f * 16 + fr) * 8;
            ah[f] = *(const s16x8*)&AH[aoff];
            al[f] = *(const s16x8*)&AL[aoff];
            bh[f] = *(const s16x8*)&BH[boff];
            bl[f] = *(const s16x8*)&BL[boff];
        }
        #pragma unroll
        for (int i = 0; i < 4; i++)
            #pragma unroll
            for (int j = 0; j < 4; j++) {
                acc[i][j] = __builtin_amdgcn_mfma_f32_16x16x32_bf16(ah[i], bh[j], acc[i][j], 0, 0, 0);
                acc[i][j] = __builtin_amdgcn_mfma_f32_16x16x32_bf16(ah[i], bl[j], acc[i][j], 0, 0, 0);
                acc[i][j] = __builtin_amdgcn_mfma_f32_16x16x32_bf16(al[i], bh[j], acc[i][j], 0, 0, 0);
            }
    }

    #pragma unroll
    for (int i = 0; i < 4; i++) {
        int mbase = m0 + wm * 64 + i * 16 + fq * 4;
        #pragma unroll
        for (int j = 0; j < 4; j++) {
            int n = n0 + wn * 64 + j * 16 + fr;
            #pragma unroll
            for (int rg = 0; rg < 4; rg++) {
                int m = mbase + rg;
                PT[(size_t)m * NROW + n] = acc[i][j][rg] + bproj[m];
            }
        }
    }
}

// ---------------------------------------------------------------------------
// GEMM1-lite (single bf16): PT rows 0..255, 768..1791. BK=32, 16 KB LDS:
// residency 8 blocks/CU (thread-capped) -> all 1280 blocks co-resident in
// ONE round, exactly 5/CU, zero tail. (BK=64/32KB capped residency at 4/CU
// -> 1.25 rounds; r9 profile: Occupancy 32.5% = avg of full + quarter-full
// rounds.) K summation order identical (strictly increasing) -> absmax same.
//   jt = (blockIdx.y < 2) ? blockIdx.y : blockIdx.y + 4
// ---------------------------------------------------------------------------
__global__ __launch_bounds__(256, 4) void gemm1_lite_kernel(
    const unsigned short* __restrict__ WH, const unsigned short* __restrict__ XH,
    const float* __restrict__ bproj, const float* __restrict__ bphase,
    float* __restrict__ PT)
{
    __shared__ __attribute__((aligned(16))) unsigned short AH[4096];
    __shared__ __attribute__((aligned(16))) unsigned short BH[4096];

    const int tid  = threadIdx.x;
    const int lane = tid & 63;
    const int w    = tid >> 6;
    const int wm   = w >> 1, wn = w & 1;
    const int yt   = blockIdx.y;
    const int jt   = (yt < 2) ? yt : yt + 4;
    const int m0   = jt * 128;
    const int n0   = blockIdx.x * 128;
    const int fr   = lane & 15;
    const int fq   = lane >> 4;

    f32x4 acc[4][4];
    #pragma unroll
    for (int i = 0; i < 4; i++)
        #pragma unroll
        for (int j = 0; j < 4; j++) acc[i][j] = (f32x4){0.f, 0.f, 0.f, 0.f};

    for (int kc = 0; kc < 32; kc++) {
        const int kbase = kc * 32;
        __syncthreads();
        #pragma unroll
        for (int t = 0; t < 2; t++) {
            int G  = w * 128 + t * 64 + lane;       // granule index 0..511
            int gm = G & 127;
            int gq = G >> 7;
            size_t offA = (size_t)(m0 + gm) * 1024 + kbase + gq * 8;
            size_t offB = (size_t)(n0 + gm) * 1024 + kbase + gq * 8;
            int ldsg = (w * 128 + t * 64) * 8;      // wave-uniform base (shorts)
            GL2LDS(WH + offA, &AH[ldsg]);
            GL2LDS(XH + offB, &BH[ldsg]);
        }
        __syncthreads();

        s16x8 ah[4], bh[4];
        #pragma unroll
        for (int f = 0; f < 4; f++) {
            int aoff = (fq * 128 + wm * 64 + f * 16 + fr) * 8;
            int boff = (fq * 128 + wn * 64 + f * 16 + fr) * 8;
            ah[f] = *(const s16x8*)&AH[aoff];
            bh[f] = *(const s16x8*)&BH[boff];
        }
        #pragma unroll
        for (int i = 0; i < 4; i++)
            #pragma unroll
            for (int j = 0; j < 4; j++)
                acc[i][j] = __builtin_amdgcn_mfma_f32_16x16x32_bf16(ah[i], bh[j], acc[i][j], 0, 0, 0);
    }

    #pragma unroll
    for (int i = 0; i < 4; i++) {
        int mbase = m0 + wm * 64 + i * 16 + fq * 4;
        #pragma unroll
        for (int j = 0; j < 4; j++) {
            int n = n0 + wn * 64 + j * 16 + fr;
            #pragma unroll
            for (int rg = 0; rg < 4; rg++) {
                int m = mbase + rg;
                float bias = (m < 1536) ? bproj[m] : bphase[m - 1536];
                PT[(size_t)m * NROW + n] = acc[i][j][rg] + bias;
            }
        }
    }
}

// ---------------------------------------------------------------------------
// Scan kernel (round-2 proven): one block per (b, k) channel. cs/sn carried
// in registers between pass 1 and pass 3.
// ---------------------------------------------------------------------------
__global__ __launch_bounds__(256) void scan_kernel(float* PT,
                                                   const float* lambda_ptr)
{
    const int bx = blockIdx.x;         // 0..1023
    const int k = bx & 255;
    const int b = bx >> 8;
    const int t = threadIdx.x;         // 0..255
    const size_t colb = (size_t)b * NSEQ;
    const size_t R = NROW;

    float* rowA  = PT + (size_t)(k)        * R + colb;  // a_raw -> rho_re
    float* rowW  = PT + (size_t)(256 + k)  * R + colb;  // w_raw -> rho_im
    float* rowP  = PT + (size_t)(512 + k)  * R + colb;  // p_raw -> g
    float* rowAl = PT + (size_t)(768 + k)  * R + colb;  // al_raw
    float* rowG  = PT + (size_t)(1024 + k) * R + colb;  // g_raw
    float* rowBe = PT + (size_t)(1280 + k) * R + colb;  // be_raw
    float* rowPq = PT + (size_t)(1536 + k) * R + colb;  // phase query

    __shared__ float s_al[NSEQ + 256];
    __shared__ float s_rr[NSEQ + 256];
    __shared__ float s_ri[NSEQ + 256];
    __shared__ float s_sa[256], s_sbr[256], s_sbi[256];

    const float lam = *lambda_ptr;

    float cs_r[16], sn_r[16];          // fully unrolled -> stays in VGPRs

    #pragma unroll
    for (int i = 0; i < 16; i++) {
        int n = i * 256 + t;
        float araw = rowA[n];
        float wraw = rowW[n];
        float praw = rowP[n];
        float alraw = rowAl[n];
        float A     = 3.0f * sigm(araw);
        float alpha = sigm(alraw);
        float omega = softplusf_(wraw);
        float ang   = fmaf(omega, log1pf((float)n), praw);
        float sn, cs;
        sincosf(ang, &sn, &cs);
        cs_r[i] = cs;
        sn_r[i] = sn;
        float amp = (1.0f - alpha) * A;
        int pidx = n + (n >> 4);
        s_al[pidx] = alpha;
        s_rr[pidx] = amp * cs;
        s_ri[pidx] = amp * sn;
    }
    __syncthreads();

    {
        float ap = 1.0f, br = 0.0f, bi = 0.0f;
        int base = t * 17;
        #pragma unroll
        for (int i = 0; i < 16; i++) {
            float a = s_al[base + i];
            br = fmaf(a, br, s_rr[base + i]);
            bi = fmaf(a, bi, s_ri[base + i]);
            ap *= a;
        }
        s_sa[t] = ap; s_sbr[t] = br; s_sbi[t] = bi;
    }
    __syncthreads();

    for (int off = 1; off < 256; off <<= 1) {
        float a2 = s_sa[t], b2r = s_sbr[t], b2i = s_sbi[t];
        float a1 = 1.0f, b1r = 0.0f, b1i = 0.0f;
        if (t >= off) { a1 = s_sa[t - off]; b1r = s_sbr[t - off]; b1i = s_sbi[t - off]; }
        __syncthreads();
        s_sa[t]  = a1 * a2;
        s_sbr[t] = fmaf(a2, b1r, b2r);
        s_sbi[t] = fmaf(a2, b1i, b2i);
        __syncthreads();
    }

    {
        float cr = 0.0f, ci = 0.0f;
        if (t > 0) { cr = s_sbr[t - 1]; ci = s_sbi[t - 1]; }
        int base = t * 17;
        #pragma unroll
        for (int i = 0; i < 16; i++) {
            float a = s_al[base + i];
            cr = fmaf(a, cr, s_rr[base + i]);
            ci = fmaf(a, ci, s_ri[base + i]);
            s_rr[base + i] = cr;
            s_ri[base + i] = ci;
        }
    }
    __syncthreads();

    #pragma unroll
    for (int i = 0; i < 16; i++) {
        int n = i * 256 + t;
        float beraw = rowBe[n];
        float graw = rowG[n];
        float pq = rowPq[n];

        float cs = cs_r[i];
        float sn = sn_r[i];

        int pidx = n + (n >> 4);
        float rr = s_rr[pidx], ri = s_ri[pidx];
        float beta = sigm(beraw);
        float g = sigm(graw);

        float readout = rr * cs + ri * sn;
        rr -= beta * readout * cs;
        ri -= beta * readout * sn;

        float modulus = sqrtf(rr * rr + ri * ri + 1e-8f);
        float scale = fmaxf(modulus, 1.0f);
        rr /= scale; ri /= scale;

        float rho_re = rr * cs + ri * sn;
        float rho_im = -rr * sn + ri * cs;

        float rho_norm = sqrtf(rho_re * rho_re + rho_im * rho_im + 1e-8f);
        float sq, cq;
        sincosf(pq, &sq, &cq);
        float pa = (rho_re * cq + rho_im * sq) / rho_norm;
        float gate = sigm(lam * pa);
        rho_re *= gate;
        rho_im *= gate;

        rowA[n] = rho_re;
        rowW[n] = rho_im;
        rowP[n] = g;
    }
}

// ---------------------------------------------------------------------------
// pack_rho: fused cross-products + transpose + bf16 split.
// ---------------------------------------------------------------------------
__global__ __launch_bounds__(256) void pack_rho_kernel(
    const float* __restrict__ PT, unsigned short* __restrict__ RTH,
    unsigned short* __restrict__ RTL)
{
    __shared__ float s_re[256 * 33];
    __shared__ float s_im[256 * 33];
    __shared__ float s_g [256 * 33];

    const int tid = threadIdx.x;
    const int r0 = blockIdx.x * 32;

    {
        int lr = tid & 31;
        int k0 = tid >> 5;       // 0..7
        for (int it = 0; it < 32; it++) {
            int k = it * 8 + k0;
            size_t go = (size_t)k * NROW + r0 + lr;
            s_re[k * 33 + lr] = PT[go];
            s_im[k * 33 + lr] = PT[(size_t)256 * NROW + go];
            s_g [k * 33 + lr] = PT[(size_t)512 * NROW + go];
        }
    }
    __syncthreads();

    const int r = tid >> 3;      // 0..31
    const int c = tid & 7;       // 0..7
    for (int i = 0; i < 16; i++) {
        int jb = (c + 8 * i) * 8;       // 0..1016, step 8
        unsigned short h[8], l[8];
        #pragma unroll
        for (int e = 0; e < 8; e++) {
            int j = jb + e;
            float v;
            if (j < 256) {
                v = s_g[j * 33 + r] * s_re[j * 33 + r];
            } else if (j < 512) {
                int k = j - 256;
                v = s_g[k * 33 + r] * s_im[k * 33 + r];
            } else if (j < 767) {
                int k = j - 512;
                float gc = 0.5f * (s_g[k * 33 + r] + s_g[(k + 1) * 33 + r]);
                v = gc * (s_re[k * 33 + r] * s_re[(k + 1) * 33 + r]
                        - s_im[k * 33 + r] * s_im[(k + 1) * 33 + r]);
            } else if (j < 1022) {
                int k = j - 767;
                float gc = 0.5f * (s_g[k * 33 + r] + s_g[(k + 1) * 33 + r]);
                v = gc * (s_re[k * 33 + r] * s_im[(k + 1) * 33 + r]
                        + s_im[k * 33 + r] * s_re[(k + 1) * 33 + r]);
            } else {
                v = 0.0f;
            }
            bf16_split(v, h[e], l[e]);
        }
        size_t off = (size_t)(r0 + r) * 1024 + jb;
        s16x8 hv, lv;
        #pragma unroll
        for (int e = 0; e < 8; e++) { hv[e] = (short)h[e]; lv[e] = (short)l[e]; }
        *(s16x8*)&RTH[off] = hv;
        *(s16x8*)&RTL[off] = lv;
    }
}

// ---------------------------------------------------------------------------
// GEMM2 (2-term: W_res bf16, rho hi+lo): out[r,d] = rs * sum_j RT[r,j]*WP[d,j]
// Wave tile 128x64 (acc 8x4), block 256d x 128r (round-8 proven: dropped out
// of top-5). Grid (128, 4) = 512 blocks = exactly 2/CU, zero tail.
// ---------------------------------------------------------------------------
__global__ __launch_bounds__(256, 2) void gemm2_kernel(
    const unsigned short* __restrict__ WPH,
    const unsigned short* __restrict__ RTH, const unsigned short* __restrict__ RTL,
    const float* __restrict__ rs_ptr, float* __restrict__ out)
{
    __shared__ __attribute__((aligned(16))) unsigned short AH[8192]; // 256x32
    __shared__ __attribute__((aligned(16))) unsigned short BH[4096]; // 128x32
    __shared__ __attribute__((aligned(16))) unsigned short BL[4096];

    const int tid  = threadIdx.x;
    const int lane = tid & 63;
    const int w    = tid >> 6;
    const int wm   = w >> 1;            // 0..1: d half (128)
    const int wn   = w & 1;             // 0..1: r half (64)
    const int m0   = blockIdx.y * 256;  // d tile
    const int n0   = blockIdx.x * 128;  // r tile
    const int fr   = lane & 15;
    const int fq   = lane >> 4;
    const float rs = *rs_ptr;

    f32x4 acc[8][4];
    #pragma unroll
    for (int i = 0; i < 8; i++)
        #pragma unroll
        for (int j = 0; j < 4; j++) acc[i][j] = (f32x4){0.f, 0.f, 0.f, 0.f};

    for (int kc = 0; kc < 32; kc++) {
        const int kbase = kc * 32;
        __syncthreads();
        // A: 1024 granules (256 rows x 4 ksubs)
        #pragma unroll
        for (int it = 0; it < 4; it++) {
            int G   = it * 256 + tid;
            int row = G & 255;
            int gq  = G >> 8;
            size_t offA = (size_t)(m0 + row) * 1024 + kbase + gq * 8;
            int ldsg = (it * 256 + w * 64) * 8;     // wave-uniform base
            GL2LDS(WPH + offA, &AH[ldsg]);
        }
        // B: 512 granules x 2 arrays
        #pragma unroll
        for (int it = 0; it < 2; it++) {
            int G   = it * 256 + tid;
            int row = G & 127;
            int gq  = G >> 7;
            size_t offB = (size_t)(n0 + row) * 1024 + kbase + gq * 8;
            int ldsg = (it * 256 + w * 64) * 8;
            GL2LDS(RTH + offB, &BH[ldsg]);
            GL2LDS(RTL + offB, &BL[ldsg]);
        }
        __syncthreads();

        s16x8 ah[8], bh[4], bl[4];
        #pragma unroll
        for (int i = 0; i < 8; i++)
            ah[i] = *(const s16x8*)&AH[(fq * 256 + wm * 128 + i * 16 + fr) * 8];
        #pragma unroll
        for (int j = 0; j < 4; j++) {
            int boff = (fq * 128 + wn * 64 + j * 16 + fr) * 8;
            bh[j] = *(const s16x8*)&BH[boff];
            bl[j] = *(const s16x8*)&BL[boff];
        }
        #pragma unroll
        for (int i = 0; i < 8; i++)
            #pragma unroll
            for (int j = 0; j < 4; j++) {
                acc[i][j] = __builtin_amdgcn_mfma_f32_16x16x32_bf16(ah[i], bh[j], acc[i][j], 0, 0, 0);
                acc[i][j] = __builtin_amdgcn_mfma_f32_16x16x32_bf16(ah[i], bl[j], acc[i][j], 0, 0, 0);
            }
    }

    #pragma unroll
    for (int i = 0; i < 8; i++) {
        int d = m0 + wm * 128 + i * 16 + fq * 4;
        #pragma unroll
        for (int j = 0; j < 4; j++) {
            int n = n0 + wn * 64 + j * 16 + fr;
            float4 v = { rs * acc[i][j][0], rs * acc[i][j][1],
                         rs * acc[i][j][2], rs * acc[i][j][3] };
            *(float4*)&out[(size_t)n * 1024 + d] = v;
        }
    }
}

// ---------------------------------------------------------------------------
extern "C" void kernel_launch(void* const* d_in, const int* in_sizes, int n_in,
                              void* d_out, int out_size, void* d_ws, size_t ws_size,
                              hipStream_t stream)
{
    const float* x      = (const float*)d_in[0];
    const float* Wproj  = (const float*)d_in[1];
    const float* bproj  = (const float*)d_in[2];
    const float* Wres   = (const float*)d_in[3];
    const float* Wphase = (const float*)d_in[4];
    const float* bphase = (const float*)d_in[5];
    const float* lam    = (const float*)d_in[6];
    const float* rs     = (const float*)d_in[7];
    float* out = (float*)d_out;

    // workspace layout (~124.8 MB):
    //   PT fp32 [1792][16384]           (117.4 MB)
    //   WH, WL bf16 [1792][1024]        (7.3 MB, after PT)
    // aliased into dead PT rows:
    //   RTH bf16 [16384][1024] = PT rows  768..1279
    //   RTL bf16 [16384][1024] = PT rows 1280..1791
    //   WPH bf16 [1024][1024]  = PT rows 0..31 (after pack_rho)
    // d_out doubles as XH/XL bf16 scratch until gemm2 overwrites it.
    float* PT = (float*)d_ws;
    unsigned short* WH  = (unsigned short*)((char*)d_ws + (size_t)JTOT * NROW * 4);
    unsigned short* WL  = WH + (size_t)JTOT * 1024;
    unsigned short* RTH = (unsigned short*)(PT + (size_t)768 * NROW);
    unsigned short* RTL = RTH + (size_t)NROW * 1024;
    unsigned short* WPH = (unsigned short*)PT;
    unsigned short* XH  = (unsigned short*)d_out;
    unsigned short* XL  = XH + (size_t)NROW * 1024;

    hipLaunchKernelGGL(split_x_kernel, dim3(NROW * D_MODEL / 1024), dim3(256), 0, stream,
                       x, XH, XL);
    hipLaunchKernelGGL(split_w_kernel, dim3(JTOT * D_MODEL / 1024), dim3(256), 0, stream,
                       Wproj, Wphase, WH, WL);
    hipLaunchKernelGGL(gemm1_full_kernel, dim3(NROW / 128, 4), dim3(256), 0, stream,
                       WH, WL, XH, XL, bproj, PT);
    hipLaunchKernelGGL(gemm1_lite_kernel, dim3(NROW / 128, 10), dim3(256), 0, stream,
                       WH, XH, bproj, bphase, PT);
    hipLaunchKernelGGL(scan_kernel, dim3(BATCH * KOSC), dim3(256), 0, stream,
                       PT, lam);
    hipLaunchKernelGGL(pack_rho_kernel, dim3(NROW / 32), dim3(256), 0, stream,
                       PT, RTH, RTL);
    hipLaunchKernelGGL(pack_wres_kernel, dim3(1024 * 1024 / 256), dim3(256), 0, stream,
                       Wres, WPH);
    hipLaunchKernelGGL(gemm2_kernel, dim3(NROW / 128, 1024 / 256), dim3(256), 0, stream,
                       WPH, RTH, RTL, rs, out);
}

// Round 11
// 502.485 us; speedup vs baseline: 1.4060x; 1.0050x over previous
//
#include <hip/hip_runtime.h>
#include <cmath>

// Problem constants
#define D_MODEL 1024
#define KOSC    256
#define NSEQ    4096
#define BATCH   4
#define NROW    (BATCH * NSEQ)   // 16384 rows (b*n)
#define JTOT    1792             // 6K proj + K phase

typedef short      s16x8 __attribute__((ext_vector_type(8)));
typedef float      f32x4 __attribute__((ext_vector_type(4)));

// async global->LDS, 16B per lane; LDS dest = wave-uniform base + lane*16
#define GL2LDS(gsrc, ldst)                                                      \
  __builtin_amdgcn_global_load_lds(                                             \
      (const __attribute__((address_space(1))) unsigned int*)(gsrc),            \
      (__attribute__((address_space(3))) unsigned int*)(ldst), 16, 0, 0)

__device__ __forceinline__ float sigm(float x) {
    return 1.0f / (1.0f + expf(-x));
}
__device__ __forceinline__ float softplusf_(float x) {
    return fmaxf(x, 0.0f) + log1pf(expf(-fabsf(x)));
}

// round-to-nearest-even bf16 split: f = hi + lo, residual ~2^-18 * |f|
__device__ __forceinline__ void bf16_split(float f, unsigned short& hi,
                                           unsigned short& lo) {
    unsigned u = __float_as_uint(f);
    unsigned r = u + 0x7FFFu + ((u >> 16) & 1u);
    hi = (unsigned short)(r >> 16);
    float fh = __uint_as_float((unsigned)hi << 16);
    float fl = f - fh;
    unsigned ul = __float_as_uint(fl);
    unsigned rl = ul + 0x7FFFu + ((ul >> 16) & 1u);
    lo = (unsigned short)(rl >> 16);
}

// ---------------------------------------------------------------------------
// split_x: x fp32 (16384x1024) -> XH, XL bf16 (in d_out scratch)
// ---------------------------------------------------------------------------
__global__ __launch_bounds__(256) void split_x_kernel(
    const float* __restrict__ x, unsigned short* __restrict__ XH,
    unsigned short* __restrict__ XL)
{
    int i = blockIdx.x * 256 + threadIdx.x;    // x4 floats
    float4 v = ((const float4*)x)[i];
    ushort4 h, l;
    bf16_split(v.x, h.x, l.x);
    bf16_split(v.y, h.y, l.y);
    bf16_split(v.z, h.z, l.z);
    bf16_split(v.w, h.w, l.w);
    ((ushort4*)XH)[i] = h;
    ((ushort4*)XL)[i] = l;
}

// ---------------------------------------------------------------------------
// split_w: [Wproj;Wphase] fp32 (1792x1024) -> WH, WL bf16
// ---------------------------------------------------------------------------
__global__ __launch_bounds__(256) void split_w_kernel(
    const float* __restrict__ Wproj, const float* __restrict__ Wphase,
    unsigned short* __restrict__ WH, unsigned short* __restrict__ WL)
{
    int i = blockIdx.x * 256 + threadIdx.x;    // x4 floats
    int elem = i << 2;
    int row = elem >> 10;
    int col = elem & 1023;
    const float* src = (row < 1536) ? (Wproj + (size_t)row * 1024 + col)
                                    : (Wphase + (size_t)(row - 1536) * 1024 + col);
    float4 v = *(const float4*)src;
    ushort4 h, l;
    bf16_split(v.x, h.x, l.x);
    bf16_split(v.y, h.y, l.y);
    bf16_split(v.z, h.z, l.z);
    bf16_split(v.w, h.w, l.w);
    ((ushort4*)WH)[i] = h;
    ((ushort4*)WL)[i] = l;
}

// ---------------------------------------------------------------------------
// pack_wres: W_res fp32 (1024 x 1022) -> WPH bf16 (1024 x 1024), padded 0
// ---------------------------------------------------------------------------
__global__ __launch_bounds__(256) void pack_wres_kernel(
    const float* __restrict__ Wres, unsigned short* __restrict__ WPH)
{
    int idx = blockIdx.x * 256 + threadIdx.x;   // 0 .. 1024*1024-1
    int d = idx >> 10;
    int j = idx & 1023;
    float v = (j < 1022) ? Wres[(size_t)d * 1022 + j] : 0.0f;
    unsigned u = __float_as_uint(v);
    unsigned r = u + 0x7FFFu + ((u >> 16) & 1u);
    WPH[idx] = (unsigned short)(r >> 16);
}

// ---------------------------------------------------------------------------
// GEMM1 merged: one launch, two block roles (both latency-bound alone at
// 16-23% MfmaUtil — co-residency overlaps full's MFMA phases with lite's
// drain stalls).
//   yt 0..3  : FULL path (3-term split-bf16), rows 256..767  (m0=(yt+2)*128)
//              — dispatched first so the long blocks don't straggle.
//   yt 4..13 : LITE path (single bf16), rows 0..255, 768..1791
//              (jt = (yy<2)? yy : yy+4, yy = yt-4)
// Per-path bodies and K-order are byte-identical to the proven r2/r10
// kernels -> absmax unchanged. Shared LDS = 32KB union -> 5 blocks/CU.
// Grid (128, 14) = 1792 blocks.
// ---------------------------------------------------------------------------
__global__ __launch_bounds__(256, 3) void gemm1_kernel(
    const unsigned short* __restrict__ WH, const unsigned short* __restrict__ WL,
    const unsigned short* __restrict__ XH, const unsigned short* __restrict__ XL,
    const float* __restrict__ bproj, const float* __restrict__ bphase,
    float* __restrict__ PT)
{
    __shared__ __attribute__((aligned(16))) unsigned short smem[16384]; // 32 KB
    unsigned short* AH = smem;            // 8KB (4096 shorts)
    unsigned short* AL = smem + 4096;
    unsigned short* BH = smem + 8192;
    unsigned short* BL = smem + 12288;

    const int tid  = threadIdx.x;
    const int lane = tid & 63;
    const int w    = tid >> 6;          // wave 0..3
    const int wm   = w >> 1, wn = w & 1;
    const int yt   = blockIdx.y;
    const int n0   = blockIdx.x * 128;  // r tile
    const int fr   = lane & 15;
    const int fq   = lane >> 4;         // 0..3

    f32x4 acc[4][4];
    #pragma unroll
    for (int i = 0; i < 4; i++)
        #pragma unroll
        for (int j = 0; j < 4; j++) acc[i][j] = (f32x4){0.f, 0.f, 0.f, 0.f};

    if (yt < 4) {
        // ---------------- FULL path: rows 256..767, 3-term ----------------
        const int m0 = (yt + 2) * 128;

        for (int kc = 0; kc < 32; kc++) {
            const int kbase = kc * 32;
            __syncthreads();
            #pragma unroll
            for (int t = 0; t < 2; t++) {
                int G  = w * 128 + t * 64 + lane;       // granule 0..511
                int gm = G & 127;
                int gq = G >> 7;
                size_t offA = (size_t)(m0 + gm) * 1024 + kbase + gq * 8;
                size_t offB = (size_t)(n0 + gm) * 1024 + kbase + gq * 8;
                int ldsg = (w * 128 + t * 64) * 8;      // wave-uniform base
                GL2LDS(WH + offA, &AH[ldsg]);
                GL2LDS(WL + offA, &AL[ldsg]);
                GL2LDS(XH + offB, &BH[ldsg]);
                GL2LDS(XL + offB, &BL[ldsg]);
            }
            __syncthreads();

            s16x8 ah[4], al[4], bh[4], bl[4];
            #pragma unroll
            for (int f = 0; f < 4; f++) {
                int aoff = (fq * 128 + wm * 64 + f * 16 + fr) * 8;
                int boff = (fq * 128 + wn * 64 + f * 16 + fr) * 8;
                ah[f] = *(const s16x8*)&AH[aoff];
                al[f] = *(const s16x8*)&AL[aoff];
                bh[f] = *(const s16x8*)&BH[boff];
                bl[f] = *(const s16x8*)&BL[boff];
            }
            #pragma unroll
            for (int i = 0; i < 4; i++)
                #pragma unroll
                for (int j = 0; j < 4; j++) {
                    acc[i][j] = __builtin_amdgcn_mfma_f32_16x16x32_bf16(ah[i], bh[j], acc[i][j], 0, 0, 0);
                    acc[i][j] = __builtin_amdgcn_mfma_f32_16x16x32_bf16(ah[i], bl[j], acc[i][j], 0, 0, 0);
                    acc[i][j] = __builtin_amdgcn_mfma_f32_16x16x32_bf16(al[i], bh[j], acc[i][j], 0, 0, 0);
                }
        }

        #pragma unroll
        for (int i = 0; i < 4; i++) {
            int mbase = m0 + wm * 64 + i * 16 + fq * 4;
            #pragma unroll
            for (int j = 0; j < 4; j++) {
                int n = n0 + wn * 64 + j * 16 + fr;
                #pragma unroll
                for (int rg = 0; rg < 4; rg++) {
                    int m = mbase + rg;
                    PT[(size_t)m * NROW + n] = acc[i][j][rg] + bproj[m];
                }
            }
        }
    } else {
        // ---------------- LITE path: rows 0..255, 768..1791, 1-term -------
        const int yy = yt - 4;
        const int jt = (yy < 2) ? yy : yy + 4;
        const int m0 = jt * 128;

        for (int kc = 0; kc < 32; kc++) {
            const int kbase = kc * 32;
            __syncthreads();
            #pragma unroll
            for (int t = 0; t < 2; t++) {
                int G  = w * 128 + t * 64 + lane;       // granule 0..511
                int gm = G & 127;
                int gq = G >> 7;
                size_t offA = (size_t)(m0 + gm) * 1024 + kbase + gq * 8;
                size_t offB = (size_t)(n0 + gm) * 1024 + kbase + gq * 8;
                int ldsg = (w * 128 + t * 64) * 8;      // wave-uniform base
                GL2LDS(WH + offA, &AH[ldsg]);
                GL2LDS(XH + offB, &BH[ldsg]);
            }
            __syncthreads();

            s16x8 ah[4], bh[4];
            #pragma unroll
            for (int f = 0; f < 4; f++) {
                int aoff = (fq * 128 + wm * 64 + f * 16 + fr) * 8;
                int boff = (fq * 128 + wn * 64 + f * 16 + fr) * 8;
                ah[f] = *(const s16x8*)&AH[aoff];
                bh[f] = *(const s16x8*)&BH[boff];
            }
            #pragma unroll
            for (int i = 0; i < 4; i++)
                #pragma unroll
                for (int j = 0; j < 4; j++)
                    acc[i][j] = __builtin_amdgcn_mfma_f32_16x16x32_bf16(ah[i], bh[j], acc[i][j], 0, 0, 0);
        }

        #pragma unroll
        for (int i = 0; i < 4; i++) {
            int mbase = m0 + wm * 64 + i * 16 + fq * 4;
            #pragma unroll
            for (int j = 0; j < 4; j++) {
                int n = n0 + wn * 64 + j * 16 + fr;
                #pragma unroll
                for (int rg = 0; rg < 4; rg++) {
                    int m = mbase + rg;
                    float bias = (m < 1536) ? bproj[m] : bphase[m - 1536];
                    PT[(size_t)m * NROW + n] = acc[i][j][rg] + bias;
                }
            }
        }
    }
}

// ---------------------------------------------------------------------------
// Scan kernel (round-2 proven): one block per (b, k) channel. cs/sn carried
// in registers between pass 1 and pass 3.
// ---------------------------------------------------------------------------
__global__ __launch_bounds__(256) void scan_kernel(float* PT,
                                                   const float* lambda_ptr)
{
    const int bx = blockIdx.x;         // 0..1023
    const int k = bx & 255;
    const int b = bx >> 8;
    const int t = threadIdx.x;         // 0..255
    const size_t colb = (size_t)b * NSEQ;
    const size_t R = NROW;

    float* rowA  = PT + (size_t)(k)        * R + colb;  // a_raw -> rho_re
    float* rowW  = PT + (size_t)(256 + k)  * R + colb;  // w_raw -> rho_im
    float* rowP  = PT + (size_t)(512 + k)  * R + colb;  // p_raw -> g
    float* rowAl = PT + (size_t)(768 + k)  * R + colb;  // al_raw
    float* rowG  = PT + (size_t)(1024 + k) * R + colb;  // g_raw
    float* rowBe = PT + (size_t)(1280 + k) * R + colb;  // be_raw
    float* rowPq = PT + (size_t)(1536 + k) * R + colb;  // phase query

    __shared__ float s_al[NSEQ + 256];
    __shared__ float s_rr[NSEQ + 256];
    __shared__ float s_ri[NSEQ + 256];
    __shared__ float s_sa[256], s_sbr[256], s_sbi[256];

    const float lam = *lambda_ptr;

    float cs_r[16], sn_r[16];          // fully unrolled -> stays in VGPRs

    #pragma unroll
    for (int i = 0; i < 16; i++) {
        int n = i * 256 + t;
        float araw = rowA[n];
        float wraw = rowW[n];
        float praw = rowP[n];
        float alraw = rowAl[n];
        float A     = 3.0f * sigm(araw);
        float alpha = sigm(alraw);
        float omega = softplusf_(wraw);
        float ang   = fmaf(omega, log1pf((float)n), praw);
        float sn, cs;
        sincosf(ang, &sn, &cs);
        cs_r[i] = cs;
        sn_r[i] = sn;
        float amp = (1.0f - alpha) * A;
        int pidx = n + (n >> 4);
        s_al[pidx] = alpha;
        s_rr[pidx] = amp * cs;
        s_ri[pidx] = amp * sn;
    }
    __syncthreads();

    {
        float ap = 1.0f, br = 0.0f, bi = 0.0f;
        int base = t * 17;
        #pragma unroll
        for (int i = 0; i < 16; i++) {
            float a = s_al[base + i];
            br = fmaf(a, br, s_rr[base + i]);
            bi = fmaf(a, bi, s_ri[base + i]);
            ap *= a;
        }
        s_sa[t] = ap; s_sbr[t] = br; s_sbi[t] = bi;
    }
    __syncthreads();

    for (int off = 1; off < 256; off <<= 1) {
        float a2 = s_sa[t], b2r = s_sbr[t], b2i = s_sbi[t];
        float a1 = 1.0f, b1r = 0.0f, b1i = 0.0f;
        if (t >= off) { a1 = s_sa[t - off]; b1r = s_sbr[t - off]; b1i = s_sbi[t - off]; }
        __syncthreads();
        s_sa[t]  = a1 * a2;
        s_sbr[t] = fmaf(a2, b1r, b2r);
        s_sbi[t] = fmaf(a2, b1i, b2i);
        __syncthreads();
    }

    {
        float cr = 0.0f, ci = 0.0f;
        if (t > 0) { cr = s_sbr[t - 1]; ci = s_sbi[t - 1]; }
        int base = t * 17;
        #pragma unroll
        for (int i = 0; i < 16; i++) {
            float a = s_al[base + i];
            cr = fmaf(a, cr, s_rr[base + i]);
            ci = fmaf(a, ci, s_ri[base + i]);
            s_rr[base + i] = cr;
            s_ri[base + i] = ci;
        }
    }
    __syncthreads();

    #pragma unroll
    for (int i = 0; i < 16; i++) {
        int n = i * 256 + t;
        float beraw = rowBe[n];
        float graw = rowG[n];
        float pq = rowPq[n];

        float cs = cs_r[i];
        float sn = sn_r[i];

        int pidx = n + (n >> 4);
        float rr = s_rr[pidx], ri = s_ri[pidx];
        float beta = sigm(beraw);
        float g = sigm(graw);

        float readout = rr * cs + ri * sn;
        rr -= beta * readout * cs;
        ri -= beta * readout * sn;

        float modulus = sqrtf(rr * rr + ri * ri + 1e-8f);
        float scale = fmaxf(modulus, 1.0f);
        rr /= scale; ri /= scale;

        float rho_re = rr * cs + ri * sn;
        float rho_im = -rr * sn + ri * cs;

        float rho_norm = sqrtf(rho_re * rho_re + rho_im * rho_im + 1e-8f);
        float sq, cq;
        sincosf(pq, &sq, &cq);
        float pa = (rho_re * cq + rho_im * sq) / rho_norm;
        float gate = sigm(lam * pa);
        rho_re *= gate;
        rho_im *= gate;

        rowA[n] = rho_re;
        rowW[n] = rho_im;
        rowP[n] = g;
    }
}

// ---------------------------------------------------------------------------
// pack_rho: fused cross-products + transpose + bf16 split.
// ---------------------------------------------------------------------------
__global__ __launch_bounds__(256) void pack_rho_kernel(
    const float* __restrict__ PT, unsigned short* __restrict__ RTH,
    unsigned short* __restrict__ RTL)
{
    __shared__ float s_re[256 * 33];
    __shared__ float s_im[256 * 33];
    __shared__ float s_g [256 * 33];

    const int tid = threadIdx.x;
    const int r0 = blockIdx.x * 32;

    {
        int lr = tid & 31;
        int k0 = tid >> 5;       // 0..7
        for (int it = 0; it < 32; it++) {
            int k = it * 8 + k0;
            size_t go = (size_t)k * NROW + r0 + lr;
            s_re[k * 33 + lr] = PT[go];
            s_im[k * 33 + lr] = PT[(size_t)256 * NROW + go];
            s_g [k * 33 + lr] = PT[(size_t)512 * NROW + go];
        }
    }
    __syncthreads();

    const int r = tid >> 3;      // 0..31
    const int c = tid & 7;       // 0..7
    for (int i = 0; i < 16; i++) {
        int jb = (c + 8 * i) * 8;       // 0..1016, step 8
        unsigned short h[8], l[8];
        #pragma unroll
        for (int e = 0; e < 8; e++) {
            int j = jb + e;
            float v;
            if (j < 256) {
                v = s_g[j * 33 + r] * s_re[j * 33 + r];
            } else if (j < 512) {
                int k = j - 256;
                v = s_g[k * 33 + r] * s_im[k * 33 + r];
            } else if (j < 767) {
                int k = j - 512;
                float gc = 0.5f * (s_g[k * 33 + r] + s_g[(k + 1) * 33 + r]);
                v = gc * (s_re[k * 33 + r] * s_re[(k + 1) * 33 + r]
                        - s_im[k * 33 + r] * s_im[(k + 1) * 33 + r]);
            } else if (j < 1022) {
                int k = j - 767;
                float gc = 0.5f * (s_g[k * 33 + r] + s_g[(k + 1) * 33 + r]);
                v = gc * (s_re[k * 33 + r] * s_im[(k + 1) * 33 + r]
                        + s_im[k * 33 + r] * s_re[(k + 1) * 33 + r]);
            } else {
                v = 0.0f;
            }
            bf16_split(v, h[e], l[e]);
        }
        size_t off = (size_t)(r0 + r) * 1024 + jb;
        s16x8 hv, lv;
        #pragma unroll
        for (int e = 0; e < 8; e++) { hv[e] = (short)h[e]; lv[e] = (short)l[e]; }
        *(s16x8*)&RTH[off] = hv;
        *(s16x8*)&RTL[off] = lv;
    }
}

// ---------------------------------------------------------------------------
// GEMM2 (2-term: W_res bf16, rho hi+lo): out[r,d] = rs * sum_j RT[r,j]*WP[d,j]
// Wave tile 128x64 (acc 8x4), block 256d x 128r (round-8 proven: dropped out
// of top-5). Grid (128, 4) = 512 blocks = exactly 2/CU, zero tail.
// ---------------------------------------------------------------------------
__global__ __launch_bounds__(256, 2) void gemm2_kernel(
    const unsigned short* __restrict__ WPH,
    const unsigned short* __restrict__ RTH, const unsigned short* __restrict__ RTL,
    const float* __restrict__ rs_ptr, float* __restrict__ out)
{
    __shared__ __attribute__((aligned(16))) unsigned short AH[8192]; // 256x32
    __shared__ __attribute__((aligned(16))) unsigned short BH[4096]; // 128x32
    __shared__ __attribute__((aligned(16))) unsigned short BL[4096];

    const int tid  = threadIdx.x;
    const int lane = tid & 63;
    const int w    = tid >> 6;
    const int wm   = w >> 1;            // 0..1: d half (128)
    const int wn   = w & 1;             // 0..1: r half (64)
    const int m0   = blockIdx.y * 256;  // d tile
    const int n0   = blockIdx.x * 128;  // r tile
    const int fr   = lane & 15;
    const int fq   = lane >> 4;
    const float rs = *rs_ptr;

    f32x4 acc[8][4];
    #pragma unroll
    for (int i = 0; i < 8; i++)
        #pragma unroll
        for (int j = 0; j < 4; j++) acc[i][j] = (f32x4){0.f, 0.f, 0.f, 0.f};

    for (int kc = 0; kc < 32; kc++) {
        const int kbase = kc * 32;
        __syncthreads();
        // A: 1024 granules (256 rows x 4 ksubs)
        #pragma unroll
        for (int it = 0; it < 4; it++) {
            int G   = it * 256 + tid;
            int row = G & 255;
            int gq  = G >> 8;
            size_t offA = (size_t)(m0 + row) * 1024 + kbase + gq * 8;
            int ldsg = (it * 256 + w * 64) * 8;     // wave-uniform base
            GL2LDS(WPH + offA, &AH[ldsg]);
        }
        // B: 512 granules x 2 arrays
        #pragma unroll
        for (int it = 0; it < 2; it++) {
            int G   = it * 256 + tid;
            int row = G & 127;
            int gq  = G >> 7;
            size_t offB = (size_t)(n0 + row) * 1024 + kbase + gq * 8;
            int ldsg = (it * 256 + w * 64) * 8;
            GL2LDS(RTH + offB, &BH[ldsg]);
            GL2LDS(RTL + offB, &BL[ldsg]);
        }
        __syncthreads();

        s16x8 ah[8], bh[4], bl[4];
        #pragma unroll
        for (int i = 0; i < 8; i++)
            ah[i] = *(const s16x8*)&AH[(fq * 256 + wm * 128 + i * 16 + fr) * 8];
        #pragma unroll
        for (int j = 0; j < 4; j++) {
            int boff = (fq * 128 + wn * 64 + j * 16 + fr) * 8;
            bh[j] = *(const s16x8*)&BH[boff];
            bl[j] = *(const s16x8*)&BL[boff];
        }
        #pragma unroll
        for (int i = 0; i < 8; i++)
            #pragma unroll
            for (int j = 0; j < 4; j++) {
                acc[i][j] = __builtin_amdgcn_mfma_f32_16x16x32_bf16(ah[i], bh[j], acc[i][j], 0, 0, 0);
                acc[i][j] = __builtin_amdgcn_mfma_f32_16x16x32_bf16(ah[i], bl[j], acc[i][j], 0, 0, 0);
            }
    }

    #pragma unroll
    for (int i = 0; i < 8; i++) {
        int d = m0 + wm * 128 + i * 16 + fq * 4;
        #pragma unroll
        for (int j = 0; j < 4; j++) {
            int n = n0 + wn * 64 + j * 16 + fr;
            float4 v = { rs * acc[i][j][0], rs * acc[i][j][1],
                         rs * acc[i][j][2], rs * acc[i][j][3] };
            *(float4*)&out[(size_t)n * 1024 + d] = v;
        }
    }
}

// ---------------------------------------------------------------------------
extern "C" void kernel_launch(void* const* d_in, const int* in_sizes, int n_in,
                              void* d_out, int out_size, void* d_ws, size_t ws_size,
                              hipStream_t stream)
{
    const float* x      = (const float*)d_in[0];
    const float* Wproj  = (const float*)d_in[1];
    const float* bproj  = (const float*)d_in[2];
    const float* Wres   = (const float*)d_in[3];
    const float* Wphase = (const float*)d_in[4];
    const float* bphase = (const float*)d_in[5];
    const float* lam    = (const float*)d_in[6];
    const float* rs     = (const float*)d_in[7];
    float* out = (float*)d_out;

    // workspace layout (~124.8 MB):
    //   PT fp32 [1792][16384]           (117.4 MB)
    //   WH, WL bf16 [1792][1024]        (7.3 MB, after PT)
    // aliased into dead PT rows:
    //   RTH bf16 [16384][1024] = PT rows  768..1279
    //   RTL bf16 [16384][1024] = PT rows 1280..1791
    //   WPH bf16 [1024][1024]  = PT rows 0..31 (after pack_rho)
    // d_out doubles as XH/XL bf16 scratch until gemm2 overwrites it.
    float* PT = (float*)d_ws;
    unsigned short* WH  = (unsigned short*)((char*)d_ws + (size_t)JTOT * NROW * 4);
    unsigned short* WL  = WH + (size_t)JTOT * 1024;
    unsigned short* RTH = (unsigned short*)(PT + (size_t)768 * NROW);
    unsigned short* RTL = RTH + (size_t)NROW * 1024;
    unsigned short* WPH = (unsigned short*)PT;
    unsigned short* XH  = (unsigned short*)d_out;
    unsigned short* XL  = XH + (size_t)NROW * 1024;

    hipLaunchKernelGGL(split_x_kernel, dim3(NROW * D_MODEL / 1024), dim3(256), 0, stream,
                       x, XH, XL);
    hipLaunchKernelGGL(split_w_kernel, dim3(JTOT * D_MODEL / 1024), dim3(256), 0, stream,
                       Wproj, Wphase, WH, WL);
    hipLaunchKernelGGL(gemm1_kernel, dim3(NROW / 128, 14), dim3(256), 0, stream,
                       WH, WL, XH, XL, bproj, bphase, PT);
    hipLaunchKernelGGL(scan_kernel, dim3(BATCH * KOSC), dim3(256), 0, stream,
                       PT, lam);
    hipLaunchKernelGGL(pack_rho_kernel, dim3(NROW / 32), dim3(256), 0, stream,
                       PT, RTH, RTL);
    hipLaunchKernelGGL(pack_wres_kernel, dim3(1024 * 1024 / 256), dim3(256), 0, stream,
                       Wres, WPH);
    hipLaunchKernelGGL(gemm2_kernel, dim3(NROW / 128, 1024 / 256), dim3(256), 0, stream,
                       WPH, RTH, RTL, rs, out);
}